// Round 1
// baseline (712.332 us; speedup 1.0000x reference)
//
#include <hip/hip_runtime.h>
#include <cmath>
#include <complex>
#include <algorithm>

#define NW      1022
#define NBIN    512
#define NFR     64
#define NB      64
#define HOPSZ   256
#define TLEN    17150   /* HOP*(F-1)+W */
#define PADL    18
#define LXLEN   17186   /* TLEN + 2*PADL */
#define NFRAMES 4096    /* NB*NFR */
#define CHUNK   512
#define VWARM   128
#define NCH     34      /* ceil(LXLEN/CHUNK) */

struct IirCoef {
  float b0,b1,b2,b3,b4,b5;
  float a1,a2,a3,a4,a5;
  float zi0,zi1,zi2,zi3,zi4;
};

// ---------------- basis generation ----------------
// Binv[kk][t], kk in [0,1024): kk<512 -> Re basis, kk>=512 -> Im basis.
// Binv[k][t]     =  scale_k/N * cos(2*pi*k*t/N) * SYN[t]
// Binv[512+k][t] = -scale_k/N * sin(2*pi*k*t/N) * SYN[t]   (0 for k=0,511)
__global__ void gen_binv(float* __restrict__ Binv) {
  int idx = blockIdx.x * 256 + threadIdx.x;
  if (idx >= 1024 * NW) return;
  int t = idx % NW, kk = idx / NW;
  int k = kk & 511;
  const float TPN = 6.2831853071795864769f / (float)NW;
  float fw = 0.5f - 0.5f * cosf((float)t * TPN);
  float den = 0.f;
  int tm = t & 255;
  #pragma unroll
  for (int j = 0; j < 4; ++j) {
    int u = tm + (j << 8);
    if (u < NW) { float w = 0.5f - 0.5f * cosf((float)u * TPN); den += w * w; }
  }
  float syn = fw / den;
  int r = (int)(((long long)k * (long long)t) % NW);
  float arg = (float)r * TPN;
  float scale = (k == 0 || k == 511) ? 1.f : 2.f;
  float val;
  if (kk < 512) val = cosf(arg) * scale * (1.f / (float)NW) * syn;
  else          val = (k == 0 || k == 511) ? 0.f
                      : -sinf(arg) * scale * (1.f / (float)NW) * syn;
  Binv[kk * NW + t] = val;
}

// Bf[t][kk]: kk<512 -> FW[t]*cos(2 pi k t/N); kk>=512 -> -FW[t]*sin(...)
__global__ void gen_bf(float* __restrict__ Bf) {
  int idx = blockIdx.x * 256 + threadIdx.x;
  if (idx >= NW * 1024) return;
  int kk = idx & 1023, t = idx >> 10;
  int k = kk & 511;
  const float TPN = 6.2831853071795864769f / (float)NW;
  float fw = 0.5f - 0.5f * cosf((float)t * TPN);
  int r = (int)(((long long)k * (long long)t) % NW);
  float arg = (float)r * TPN;
  float val = (kk < 512) ? fw * cosf(arg) : -fw * sinf(arg);
  Bf[t * 1024 + kk] = val;
}

// ---------------- input transpose: x (b,k,f,ri) -> A1[fid=b*64+f][kk=ri*512+k]
__global__ __launch_bounds__(256) void build_a1(const float* __restrict__ x,
                                                float* __restrict__ A1) {
  __shared__ float tile[32][129];  // [k-local][f*2+ri]
  int b  = blockIdx.x >> 4;
  int k0 = (blockIdx.x & 15) << 5;
  int tid = threadIdx.x;
  #pragma unroll
  for (int e = 0; e < 16; ++e) {
    int lin = tid + e * 256;        // i*128 + c
    int i = lin >> 7, c = lin & 127;
    tile[i][c] = x[(b * 512 + k0 + i) * 128 + c];
  }
  __syncthreads();
  #pragma unroll
  for (int e = 0; e < 16; ++e) {
    int lin = tid + e * 256;        // c*32 + i
    int c = lin >> 5, i = lin & 31;
    int f = c >> 1, ri = c & 1;
    A1[(b * 64 + f) * 1024 + ri * 512 + k0 + i] = tile[i][c];
  }
}

// ---------------- generic fp32 GEMM: C[M,N] = A[M,K] * B[K,N], BM=64 BN=128 BK=16
__global__ __launch_bounds__(256) void gemm_64x128(
    const float* __restrict__ A, const float* __restrict__ B,
    float* __restrict__ C, int M, int N, int K, int lda, int ldb, int ldc) {
  __shared__ __align__(16) float As[16][68];
  __shared__ __align__(16) float Bs[16][140];   // swizzled: np = n + ((n>>5)<<2)
  const int tid = threadIdx.x;
  const int tx = tid & 15, ty = tid >> 4;
  const int n0 = blockIdx.x * 128, m0 = blockIdx.y * 64;
  float acc[4][8];
  #pragma unroll
  for (int i = 0; i < 4; ++i)
    #pragma unroll
    for (int j = 0; j < 8; ++j) acc[i][j] = 0.f;

  const int npb = (tx << 3) + ((tx >> 2) << 2);  // swizzled base col for reads

  for (int k0 = 0; k0 < K; k0 += 16) {
    #pragma unroll
    for (int e = 0; e < 4; ++e) {
      int lin = tid + e * 256;       // m*16 + kk
      int m = lin >> 4, kk = lin & 15;
      int gk = k0 + kk;
      As[kk][m] = (gk < K) ? A[(m0 + m) * lda + gk] : 0.f;
    }
    #pragma unroll
    for (int e = 0; e < 8; ++e) {
      int lin = tid + e * 256;       // kk*128 + n
      int kk = lin >> 7, n = lin & 127;
      int gk = k0 + kk, gn = n0 + n;
      int np = n + ((n >> 5) << 2);
      Bs[kk][np] = (gk < K && gn < N) ? B[gk * ldb + gn] : 0.f;
    }
    __syncthreads();
    #pragma unroll
    for (int kk = 0; kk < 16; ++kk) {
      float4 a4  = *(const float4*)&As[kk][ty << 2];
      float4 b4a = *(const float4*)&Bs[kk][npb];
      float4 b4b = *(const float4*)&Bs[kk][npb + 4];
      float av[4] = {a4.x, a4.y, a4.z, a4.w};
      float bv[8] = {b4a.x, b4a.y, b4a.z, b4a.w, b4b.x, b4b.y, b4b.z, b4b.w};
      #pragma unroll
      for (int i = 0; i < 4; ++i)
        #pragma unroll
        for (int j = 0; j < 8; ++j)
          acc[i][j] = fmaf(av[i], bv[j], acc[i][j]);
    }
    __syncthreads();
  }
  #pragma unroll
  for (int i = 0; i < 4; ++i) {
    int gm = m0 + (ty << 2) + i;
    #pragma unroll
    for (int j = 0; j < 8; ++j) {
      int gn = n0 + (tx << 3) + j;
      if (gn < N) C[gm * ldc + gn] = acc[i][j];
    }
  }
}

// ---------------- overlap-add ----------------
__global__ void overlap_add(const float* __restrict__ frames, float* __restrict__ s) {
  int idx = blockIdx.x * 256 + threadIdx.x;
  if (idx >= NB * TLEN) return;
  int b = idx / TLEN, tau = idx % TLEN;
  int fhi = tau >> 8;
  int flo = fhi - 3; if (flo < 0) flo = 0;
  if (fhi > 63) fhi = 63;
  float sum = 0.f;
  for (int f = flo; f <= fhi; ++f) {
    int off = tau - (f << 8);
    if (off < NW) sum += frames[(b * 64 + f) * NW + off];
  }
  s[idx] = sum;
}

// ---------------- reflect-pad ----------------
__global__ void build_xe(const float* __restrict__ s, float* __restrict__ xe) {
  int idx = blockIdx.x * 256 + threadIdx.x;
  if (idx >= NB * LXLEN) return;
  int row = idx / LXLEN, i = idx % LXLEN;
  const float* sr = s + row * TLEN;
  float v;
  if (i < PADL)                 v = 2.f * sr[0] - sr[PADL - i];
  else if (i < PADL + TLEN)     v = sr[i - PADL];
  else { int j = i - (PADL + TLEN); v = 2.f * sr[TLEN - 1] - sr[TLEN - 2 - j]; }
  xe[row * LXLEN + i] = v;
}

// ---------------- IIR (direct form II transposed), chunked with warm-up -------
#define IIR_STEP(x, y)                                   \
  float y = fmaf(cf.b0, (x), z0);                        \
  z0 = fmaf(-cf.a1, y, fmaf(cf.b1, (x), z1));            \
  z1 = fmaf(-cf.a2, y, fmaf(cf.b2, (x), z2));            \
  z2 = fmaf(-cf.a3, y, fmaf(cf.b3, (x), z3));            \
  z3 = fmaf(-cf.a4, y, fmaf(cf.b4, (x), z4));            \
  z4 = fmaf(-cf.a5, y, cf.b5 * (x));

__global__ __launch_bounds__(64) void iir_fwd(const float* __restrict__ xe,
                                              float* __restrict__ y1, IirCoef cf) {
  int task = blockIdx.x * 64 + threadIdx.x;
  if (task >= NB * NCH) return;
  int row = task / NCH, ch = task % NCH;
  const float* xr = xe + row * LXLEN;
  float* yr = y1 + row * LXLEN;
  float z0, z1, z2, z3, z4;
  int start = ch * CHUNK;
  int i;
  if (ch == 0) {
    float x0 = xr[0];
    z0 = cf.zi0 * x0; z1 = cf.zi1 * x0; z2 = cf.zi2 * x0;
    z3 = cf.zi3 * x0; z4 = cf.zi4 * x0;
    i = 0;
  } else {
    z0 = z1 = z2 = z3 = z4 = 0.f;
    i = start - VWARM;
    #pragma unroll 4
    for (; i < start; ++i) { float x = xr[i]; IIR_STEP(x, y); (void)y; }
  }
  int end = start + CHUNK; if (end > LXLEN) end = LXLEN;
  #pragma unroll 4
  for (; i < end; ++i) {
    float x = xr[i];
    IIR_STEP(x, y);
    yr[i] = y;
  }
}

// backward pass on reversed y1; writes filt[t] = y2r[17167 - t] region
__global__ __launch_bounds__(64) void iir_bwd(const float* __restrict__ y1,
                                              float* __restrict__ filt, IirCoef cf) {
  int task = blockIdx.x * 64 + threadIdx.x;
  if (task >= NB * NCH) return;
  int row = task / NCH, ch = task % NCH;
  const float* yr = y1 + row * LXLEN;   // reversed access
  float* fr = filt + row * TLEN;
  float z0, z1, z2, z3, z4;
  int start = ch * CHUNK;
  int i;
  if (ch == 0) {
    float x0 = yr[LXLEN - 1];
    z0 = cf.zi0 * x0; z1 = cf.zi1 * x0; z2 = cf.zi2 * x0;
    z3 = cf.zi3 * x0; z4 = cf.zi4 * x0;
    i = 0;
  } else {
    z0 = z1 = z2 = z3 = z4 = 0.f;
    i = start - VWARM;
    #pragma unroll 4
    for (; i < start; ++i) { float x = yr[LXLEN - 1 - i]; IIR_STEP(x, y); (void)y; }
  }
  int end = start + CHUNK; if (end > LXLEN) end = LXLEN;
  #pragma unroll 4
  for (; i < end; ++i) {
    float x = yr[LXLEN - 1 - i];
    IIR_STEP(x, y);
    if (i >= PADL && i < PADL + TLEN) fr[(PADL + TLEN - 1) - i] = y;
  }
}

// ---------------- frame gather for analysis GEMM ----------------
__global__ void build_a2(const float* __restrict__ filt, float* __restrict__ A2) {
  int idx = blockIdx.x * 256 + threadIdx.x;
  if (idx >= NFRAMES * NW) return;
  int fid = idx / NW, t = idx % NW;
  int b = fid >> 6, f = fid & 63;
  A2[idx] = filt[b * TLEN + (f << 8) + t];
}

// ---------------- output transpose: Out2[fid][ri*512+k] -> out[b][k][f][ri] ---
__global__ __launch_bounds__(256) void transpose_out(const float* __restrict__ Out2,
                                                     float* __restrict__ out) {
  __shared__ float tile[128][33];  // [c=f*2+ri][k-local]
  int b  = blockIdx.x >> 4;
  int k0 = (blockIdx.x & 15) << 5;
  int tid = threadIdx.x;
  #pragma unroll
  for (int e = 0; e < 16; ++e) {
    int lin = tid + e * 256;         // c*32 + i
    int c = lin >> 5, i = lin & 31;
    int f = c >> 1, ri = c & 1;
    tile[c][i] = Out2[(b * 64 + f) * 1024 + ri * 512 + k0 + i];
  }
  __syncthreads();
  #pragma unroll
  for (int e = 0; e < 16; ++e) {
    int lin = tid + e * 256;         // i*128 + c
    int i = lin >> 7, c = lin & 127;
    out[(b * 512 + k0 + i) * 128 + c] = tile[c][i];
  }
}

// ---------------- host: butter(5,0.5) + lfilter_zi, replicating reference ----
static void solve5(double M[5][5], double v[5], double outv[5]) {
  for (int col = 0; col < 5; ++col) {
    int piv = col;
    for (int r = col + 1; r < 5; ++r)
      if (std::fabs(M[r][col]) > std::fabs(M[piv][col])) piv = r;
    if (piv != col) {
      for (int c = 0; c < 5; ++c) std::swap(M[col][c], M[piv][c]);
      std::swap(v[col], v[piv]);
    }
    double d = M[col][col];
    for (int r = col + 1; r < 5; ++r) {
      double f = M[r][col] / d;
      for (int c = col; c < 5; ++c) M[r][c] -= f * M[col][c];
      v[r] -= f * v[col];
    }
  }
  for (int r = 4; r >= 0; --r) {
    double s = v[r];
    for (int c = r + 1; c < 5; ++c) s -= M[r][c] * outv[c];
    outv[r] = s / M[r][r];
  }
}

static IirCoef make_coef() {
  const double PI = 3.14159265358979323846;
  std::complex<double> p[5];
  for (int i = 0; i < 5; ++i) {
    double m = -4.0 + 2.0 * i;
    p[i] = -std::exp(std::complex<double>(0.0, PI * m / 10.0));
  }
  double fs = 2.0;
  double warped = 2.0 * fs * std::tan(PI * 0.5 / fs);
  for (int i = 0; i < 5; ++i) p[i] *= warped;
  double kgain = std::pow(warped, 5.0);
  double fs2 = 2.0 * fs;
  std::complex<double> pd[5], prod(1.0, 0.0);
  for (int i = 0; i < 5; ++i) {
    pd[i] = (fs2 + p[i]) / (fs2 - p[i]);
    prod *= (fs2 - p[i]);
  }
  double kd = kgain * std::real(1.0 / prod);
  double b[6] = {kd, 5 * kd, 10 * kd, 10 * kd, 5 * kd, kd};
  std::complex<double> c[6] = {{1,0},{0,0},{0,0},{0,0},{0,0},{0,0}};
  for (int i = 0; i < 5; ++i)
    for (int j = i + 1; j >= 1; --j)
      c[j] -= pd[i] * c[j - 1];
  double a[6]; for (int i = 0; i < 6; ++i) a[i] = c[i].real();
  // zi: M = I - A_f; A_f[r][0] = -a[r+1]; A_f[r][r+1] = 1 (r<4)
  double M[5][5], v[5];
  for (int r = 0; r < 5; ++r)
    for (int cc = 0; cc < 5; ++cc) {
      double Af = 0.0;
      if (cc == 0) Af = -a[r + 1];
      if (cc == r + 1) Af = 1.0;
      M[r][cc] = (r == cc ? 1.0 : 0.0) - Af;
    }
  for (int r = 0; r < 5; ++r) v[r] = b[r + 1] - a[r + 1] * b[0];
  double zi[5];
  solve5(M, v, zi);
  IirCoef cf;
  cf.b0 = (float)b[0]; cf.b1 = (float)b[1]; cf.b2 = (float)b[2];
  cf.b3 = (float)b[3]; cf.b4 = (float)b[4]; cf.b5 = (float)b[5];
  cf.a1 = (float)a[1]; cf.a2 = (float)a[2]; cf.a3 = (float)a[3];
  cf.a4 = (float)a[4]; cf.a5 = (float)a[5];
  cf.zi0 = (float)zi[0]; cf.zi1 = (float)zi[1]; cf.zi2 = (float)zi[2];
  cf.zi3 = (float)zi[3]; cf.zi4 = (float)zi[4];
  return cf;
}

extern "C" void kernel_launch(void* const* d_in, const int* in_sizes, int n_in,
                              void* d_out, int out_size, void* d_ws, size_t ws_size,
                              hipStream_t stream) {
  const float* x = (const float*)d_in[0];
  float* out = (float*)d_out;

  // workspace layout (floats)
  float* ws   = (float*)d_ws;
  float* Binv = ws;                       // 1024*1022
  float* Bf   = Binv + 1024 * NW;         // 1022*1024
  float* A1   = Bf + NW * 1024;           // 4096*1024  (reused as Out2)
  float* Fr   = A1 + NFRAMES * 1024;      // 4096*1022  (reused as A2)
  float* Sg   = Fr + NFRAMES * NW;        // 64*17150
  float* Xe   = Sg + NB * TLEN;           // 64*17186
  float* Y1   = Xe + NB * LXLEN;          // 64*17186
  float* Ft   = Y1 + NB * LXLEN;          // 64*17150
  size_t need = (size_t)(Ft + NB * TLEN - ws) * sizeof(float);
  if (ws_size < need) return;  // insufficient scratch -> visible failure

  IirCoef cf = make_coef();

  gen_binv<<<(1024 * NW + 255) / 256, 256, 0, stream>>>(Binv);
  gen_bf<<<(NW * 1024 + 255) / 256, 256, 0, stream>>>(Bf);
  build_a1<<<1024, 256, 0, stream>>>(x, A1);
  gemm_64x128<<<dim3(8, 64), 256, 0, stream>>>(A1, Binv, Fr,
      NFRAMES, NW, 1024, 1024, NW, NW);
  overlap_add<<<(NB * TLEN + 255) / 256, 256, 0, stream>>>(Fr, Sg);
  build_xe<<<(NB * LXLEN + 255) / 256, 256, 0, stream>>>(Sg, Xe);
  iir_fwd<<<(NB * NCH + 63) / 64, 64, 0, stream>>>(Xe, Y1, cf);
  iir_bwd<<<(NB * NCH + 63) / 64, 64, 0, stream>>>(Y1, Ft, cf);
  build_a2<<<(NFRAMES * NW + 255) / 256, 256, 0, stream>>>(Ft, Fr);
  gemm_64x128<<<dim3(8, 64), 256, 0, stream>>>(Fr, Bf, A1,
      NFRAMES, 1024, NW, NW, 1024, 1024);
  transpose_out<<<1024, 256, 0, stream>>>(A1, out);
}

// Round 2
// 255.815 us; speedup vs baseline: 2.7846x; 2.7846x over previous
//
#include <hip/hip_runtime.h>
#include <cmath>
#include <complex>
#include <algorithm>

#define NW      1022
#define NB      64
#define TLEN    17150   /* HOP*(F-1)+W */
#define PADL    18
#define LXLEN   17186   /* TLEN + 2*PADL */
#define NFRAMES 4096    /* NB*64 */
#define CHUNK   512
#define VWARM   128
#define NCH     34      /* ceil(LXLEN/CHUNK) */
#define GK      1024    /* padded K for both GEMMs */

typedef __attribute__((ext_vector_type(8))) short short8;
typedef __attribute__((ext_vector_type(4))) float floatx4;

struct IirCoef {
  float b0,b1,b2,b3,b4,b5;
  float a1,a2,a3,a4,a5;
  float zi0,zi1,zi2,zi3,zi4;
};

static __device__ __forceinline__ ushort f2bf(float f) {
  uint32_t u = __builtin_bit_cast(uint32_t, f);
  uint32_t r = (u + 0x7FFFu + ((u >> 16) & 1u)) >> 16;   // RNE
  return (ushort)r;
}

// fp32-exact (k*t) mod 1022 for k*t < 2^24, then radians in [0, 2pi)
static __device__ __forceinline__ float phase_mod(int k, int t) {
  const float TPN = 6.2831853071795864769f / 1022.f;
  float kt = (float)(k * t);                 // exact: < 2^24
  float q = floorf(kt * (1.0f / 1022.0f));
  float r = kt - q * 1022.0f;
  if (r < 0.f) r += 1022.f;
  if (r >= 1022.f) r -= 1022.f;
  return r * TPN;
}

// ---------------- basis generation (transposed, bf16, padded to 1024) -------
// BT1[n=t][k=kk]: irfft basis * SYN window. Rows t>=1022 are zero.
__global__ void gen_bt1(ushort* __restrict__ BT1) {
  int idx = blockIdx.x * 256 + threadIdx.x;   // 1024*1024
  int t = idx >> 10, kk = idx & 1023;
  int k = kk & 511;
  float val = 0.f;
  if (t < NW) {
    const float TPN = 6.2831853071795864769f / 1022.f;
    float fw = 0.5f - 0.5f * __cosf((float)t * TPN);
    float den = 0.f;
    int tm = t & 255;
    #pragma unroll
    for (int j = 0; j < 4; ++j) {
      int u = tm + (j << 8);
      if (u < NW) { float w = 0.5f - 0.5f * __cosf((float)u * TPN); den += w * w; }
    }
    float syn = fw / den;
    float arg = phase_mod(k, t);
    float scale = (k == 0 || k == 511) ? 1.f : 2.f;
    if (kk < 512) val = __cosf(arg) * scale * (1.f / 1022.f) * syn;
    else          val = (k == 0 || k == 511) ? 0.f
                        : -__sinf(arg) * scale * (1.f / 1022.f) * syn;
  }
  BT1[idx] = f2bf(val);
}

// BT2[n=kk][k=t]: forward rfft basis * FWD window. Cols t>=1022 are zero.
__global__ void gen_bt2(ushort* __restrict__ BT2) {
  int idx = blockIdx.x * 256 + threadIdx.x;   // 1024*1024
  int kk = idx >> 10, t = idx & 1023;
  int k = kk & 511;
  float val = 0.f;
  if (t < NW) {
    const float TPN = 6.2831853071795864769f / 1022.f;
    float fw = 0.5f - 0.5f * __cosf((float)t * TPN);
    float arg = phase_mod(k, t);
    val = (kk < 512) ? fw * __cosf(arg) : -fw * __sinf(arg);
  }
  BT2[idx] = f2bf(val);
}

// ---------------- input transpose: x (b,k,f,ri) -> A1[b*64+f][ri*512+k] bf16
__global__ __launch_bounds__(256) void build_a1(const float* __restrict__ x,
                                                ushort* __restrict__ A1) {
  __shared__ float tile[32][129];
  int b  = blockIdx.x >> 4;
  int k0 = (blockIdx.x & 15) << 5;
  int tid = threadIdx.x;
  #pragma unroll
  for (int e = 0; e < 16; ++e) {
    int lin = tid + e * 256;
    int i = lin >> 7, c = lin & 127;
    tile[i][c] = x[(b * 512 + k0 + i) * 128 + c];
  }
  __syncthreads();
  #pragma unroll
  for (int e = 0; e < 16; ++e) {
    int lin = tid + e * 256;
    int c = lin >> 5, i = lin & 31;
    int f = c >> 1, ri = c & 1;
    A1[(b * 64 + f) * 1024 + ri * 512 + k0 + i] = f2bf(tile[i][c]);
  }
}

// ---------------- bf16 MFMA GEMM: C[4096,1024] = A[4096,GK] * Bt[1024,GK]^T --
// 128x128 tile, BK=64, 4 waves (2x2), wave tile 64x64, read-side XOR swizzle
// (chunk ^= row&7) realized via pre-swizzled global source for global_load_lds.
#define GLOAD16(gsrc, ldst) \
  __builtin_amdgcn_global_load_lds( \
      (const __attribute__((address_space(1))) void*)(gsrc), \
      (__attribute__((address_space(3))) void*)(ldst), 16, 0, 0)

__global__ __launch_bounds__(256) void gemm_mfma(
    const ushort* __restrict__ A, const ushort* __restrict__ Bt,
    float* __restrict__ C) {
  __shared__ __align__(16) ushort As[128 * 64];
  __shared__ __align__(16) ushort Bs[128 * 64];
  const int tid = threadIdx.x;
  const int wid = tid >> 6, lane = tid & 63;
  const int m0 = blockIdx.y * 128, n0 = blockIdx.x * 128;
  const int warp_m = wid >> 1, warp_n = wid & 1;

  floatx4 acc[4][4];
  #pragma unroll
  for (int i = 0; i < 4; ++i)
    #pragma unroll
    for (int j = 0; j < 4; ++j) acc[i][j] = (floatx4){0.f, 0.f, 0.f, 0.f};

  // staging: pass p covers rows p*32 + wid*8 + (lane>>3), chunk lane&7 (swizzled src)
  const int lr = lane >> 3;          // 0..7
  const int lc = lane & 7;           // chunk
  const int swz = lc ^ lr;           // inverse-swizzled source chunk
  const ushort* aBase = A  + (size_t)(m0 + wid * 8 + lr) * GK + swz * 8;
  const ushort* bBase = Bt + (size_t)(n0 + wid * 8 + lr) * GK + swz * 8;
  ushort* aDst = As + (wid * 8) * 64;
  ushort* bDst = Bs + (wid * 8) * 64;

  // fragment read geometry
  const int lane15 = lane & 15;
  const int g = lane >> 4;           // k-group
  const int rx = lane & 7;           // row&7 for swizzle
  const int arow = warp_m * 64 + lane15;
  const int brow = warp_n * 64 + lane15;

  for (int k0 = 0; k0 < GK; k0 += 64) {
    #pragma unroll
    for (int p = 0; p < 4; ++p) {
      GLOAD16(aBase + (size_t)(p * 32) * GK + k0, aDst + p * 2048);
      GLOAD16(bBase + (size_t)(p * 32) * GK + k0, bDst + p * 2048);
    }
    __syncthreads();   // compiler emits vmcnt(0) drain before barrier
    #pragma unroll
    for (int ks = 0; ks < 2; ++ks) {
      short8 af[4], bfr[4];
      const int chunk = ((ks << 2) + g) ^ rx;
      #pragma unroll
      for (int fm = 0; fm < 4; ++fm)
        af[fm] = *(const short8*)(As + (arow + fm * 16) * 64 + chunk * 8);
      #pragma unroll
      for (int fn = 0; fn < 4; ++fn)
        bfr[fn] = *(const short8*)(Bs + (brow + fn * 16) * 64 + chunk * 8);
      #pragma unroll
      for (int fm = 0; fm < 4; ++fm)
        #pragma unroll
        for (int fn = 0; fn < 4; ++fn)
          acc[fm][fn] = __builtin_amdgcn_mfma_f32_16x16x32_bf16(
              af[fm], bfr[fn], acc[fm][fn], 0, 0, 0);
    }
    __syncthreads();
  }

  #pragma unroll
  for (int fm = 0; fm < 4; ++fm) {
    #pragma unroll
    for (int fn = 0; fn < 4; ++fn) {
      #pragma unroll
      for (int i = 0; i < 4; ++i) {
        int gm = m0 + warp_m * 64 + fm * 16 + g * 4 + i;
        int gn = n0 + warp_n * 64 + fn * 16 + lane15;
        C[(size_t)gm * 1024 + gn] = acc[fm][fn][i];
      }
    }
  }
}

// ---------------- overlap-add (frames stride 1024 now) ----------------
__global__ void overlap_add(const float* __restrict__ frames, float* __restrict__ s) {
  int idx = blockIdx.x * 256 + threadIdx.x;
  if (idx >= NB * TLEN) return;
  int b = idx / TLEN, tau = idx % TLEN;
  int fhi = tau >> 8;
  int flo = fhi - 3; if (flo < 0) flo = 0;
  if (fhi > 63) fhi = 63;
  float sum = 0.f;
  for (int f = flo; f <= fhi; ++f) {
    int off = tau - (f << 8);
    if (off < NW) sum += frames[(size_t)(b * 64 + f) * 1024 + off];
  }
  s[idx] = sum;
}

// ---------------- reflect-pad ----------------
__global__ void build_xe(const float* __restrict__ s, float* __restrict__ xe) {
  int idx = blockIdx.x * 256 + threadIdx.x;
  if (idx >= NB * LXLEN) return;
  int row = idx / LXLEN, i = idx % LXLEN;
  const float* sr = s + row * TLEN;
  float v;
  if (i < PADL)                 v = 2.f * sr[0] - sr[PADL - i];
  else if (i < PADL + TLEN)     v = sr[i - PADL];
  else { int j = i - (PADL + TLEN); v = 2.f * sr[TLEN - 1] - sr[TLEN - 2 - j]; }
  xe[row * LXLEN + i] = v;
}

// ---------------- IIR (DF2T), chunked with zero-state warm-up ----------------
#define IIR_STEP(x, y)                                   \
  float y = fmaf(cf.b0, (x), z0);                        \
  z0 = fmaf(-cf.a1, y, fmaf(cf.b1, (x), z1));            \
  z1 = fmaf(-cf.a2, y, fmaf(cf.b2, (x), z2));            \
  z2 = fmaf(-cf.a3, y, fmaf(cf.b3, (x), z3));            \
  z3 = fmaf(-cf.a4, y, fmaf(cf.b4, (x), z4));            \
  z4 = fmaf(-cf.a5, y, cf.b5 * (x));

__global__ __launch_bounds__(64) void iir_fwd(const float* __restrict__ xe,
                                              float* __restrict__ y1, IirCoef cf) {
  int task = blockIdx.x * 64 + threadIdx.x;
  if (task >= NB * NCH) return;
  int row = task / NCH, ch = task % NCH;
  const float* xr = xe + row * LXLEN;
  float* yr = y1 + row * LXLEN;
  float z0, z1, z2, z3, z4;
  int start = ch * CHUNK;
  int i;
  if (ch == 0) {
    float x0 = xr[0];
    z0 = cf.zi0 * x0; z1 = cf.zi1 * x0; z2 = cf.zi2 * x0;
    z3 = cf.zi3 * x0; z4 = cf.zi4 * x0;
    i = 0;
  } else {
    z0 = z1 = z2 = z3 = z4 = 0.f;
    i = start - VWARM;
    #pragma unroll 4
    for (; i < start; ++i) { float x = xr[i]; IIR_STEP(x, y); (void)y; }
  }
  int end = start + CHUNK; if (end > LXLEN) end = LXLEN;
  #pragma unroll 4
  for (; i < end; ++i) {
    float x = xr[i];
    IIR_STEP(x, y);
    yr[i] = y;
  }
}

__global__ __launch_bounds__(64) void iir_bwd(const float* __restrict__ y1,
                                              float* __restrict__ filt, IirCoef cf) {
  int task = blockIdx.x * 64 + threadIdx.x;
  if (task >= NB * NCH) return;
  int row = task / NCH, ch = task % NCH;
  const float* yr = y1 + row * LXLEN;
  float* fr = filt + row * TLEN;
  float z0, z1, z2, z3, z4;
  int start = ch * CHUNK;
  int i;
  if (ch == 0) {
    float x0 = yr[LXLEN - 1];
    z0 = cf.zi0 * x0; z1 = cf.zi1 * x0; z2 = cf.zi2 * x0;
    z3 = cf.zi3 * x0; z4 = cf.zi4 * x0;
    i = 0;
  } else {
    z0 = z1 = z2 = z3 = z4 = 0.f;
    i = start - VWARM;
    #pragma unroll 4
    for (; i < start; ++i) { float x = yr[LXLEN - 1 - i]; IIR_STEP(x, y); (void)y; }
  }
  int end = start + CHUNK; if (end > LXLEN) end = LXLEN;
  #pragma unroll 4
  for (; i < end; ++i) {
    float x = yr[LXLEN - 1 - i];
    IIR_STEP(x, y);
    if (i >= PADL && i < PADL + TLEN) fr[(PADL + TLEN - 1) - i] = y;
  }
}

// ---------------- frame gather -> bf16 A2 (K padded to 1024) ----------------
__global__ void build_a2(const float* __restrict__ filt, ushort* __restrict__ A2) {
  int idx = blockIdx.x * 256 + threadIdx.x;
  if (idx >= NFRAMES * 1024) return;
  int fid = idx >> 10, t = idx & 1023;
  int b = fid >> 6, f = fid & 63;
  float v = (t < NW) ? filt[b * TLEN + (f << 8) + t] : 0.f;
  A2[idx] = f2bf(v);
}

// ---------------- output transpose: Out2[fid][ri*512+k] -> out[b][k][f][ri] --
__global__ __launch_bounds__(256) void transpose_out(const float* __restrict__ Out2,
                                                     float* __restrict__ out) {
  __shared__ float tile[128][33];
  int b  = blockIdx.x >> 4;
  int k0 = (blockIdx.x & 15) << 5;
  int tid = threadIdx.x;
  #pragma unroll
  for (int e = 0; e < 16; ++e) {
    int lin = tid + e * 256;
    int c = lin >> 5, i = lin & 31;
    int f = c >> 1, ri = c & 1;
    tile[c][i] = Out2[(size_t)(b * 64 + f) * 1024 + ri * 512 + k0 + i];
  }
  __syncthreads();
  #pragma unroll
  for (int e = 0; e < 16; ++e) {
    int lin = tid + e * 256;
    int i = lin >> 7, c = lin & 127;
    out[(b * 512 + k0 + i) * 128 + c] = tile[c][i];
  }
}

// ---------------- host: butter(5,0.5) + lfilter_zi ----------------
static void solve5(double M[5][5], double v[5], double outv[5]) {
  for (int col = 0; col < 5; ++col) {
    int piv = col;
    for (int r = col + 1; r < 5; ++r)
      if (std::fabs(M[r][col]) > std::fabs(M[piv][col])) piv = r;
    if (piv != col) {
      for (int c = 0; c < 5; ++c) std::swap(M[col][c], M[piv][c]);
      std::swap(v[col], v[piv]);
    }
    double d = M[col][col];
    for (int r = col + 1; r < 5; ++r) {
      double f = M[r][col] / d;
      for (int c = col; c < 5; ++c) M[r][c] -= f * M[col][c];
      v[r] -= f * v[col];
    }
  }
  for (int r = 4; r >= 0; --r) {
    double s = v[r];
    for (int c = r + 1; c < 5; ++c) s -= M[r][c] * outv[c];
    outv[r] = s / M[r][r];
  }
}

static IirCoef make_coef() {
  const double PI = 3.14159265358979323846;
  std::complex<double> p[5];
  for (int i = 0; i < 5; ++i) {
    double m = -4.0 + 2.0 * i;
    p[i] = -std::exp(std::complex<double>(0.0, PI * m / 10.0));
  }
  double fs = 2.0;
  double warped = 2.0 * fs * std::tan(PI * 0.5 / fs);
  for (int i = 0; i < 5; ++i) p[i] *= warped;
  double kgain = std::pow(warped, 5.0);
  double fs2 = 2.0 * fs;
  std::complex<double> pd[5], prod(1.0, 0.0);
  for (int i = 0; i < 5; ++i) {
    pd[i] = (fs2 + p[i]) / (fs2 - p[i]);
    prod *= (fs2 - p[i]);
  }
  double kd = kgain * std::real(1.0 / prod);
  double b[6] = {kd, 5 * kd, 10 * kd, 10 * kd, 5 * kd, kd};
  std::complex<double> c[6] = {{1,0},{0,0},{0,0},{0,0},{0,0},{0,0}};
  for (int i = 0; i < 5; ++i)
    for (int j = i + 1; j >= 1; --j)
      c[j] -= pd[i] * c[j - 1];
  double a[6]; for (int i = 0; i < 6; ++i) a[i] = c[i].real();
  double M[5][5], v[5];
  for (int r = 0; r < 5; ++r)
    for (int cc = 0; cc < 5; ++cc) {
      double Af = 0.0;
      if (cc == 0) Af = -a[r + 1];
      if (cc == r + 1) Af = 1.0;
      M[r][cc] = (r == cc ? 1.0 : 0.0) - Af;
    }
  for (int r = 0; r < 5; ++r) v[r] = b[r + 1] - a[r + 1] * b[0];
  double zi[5];
  solve5(M, v, zi);
  IirCoef cf;
  cf.b0 = (float)b[0]; cf.b1 = (float)b[1]; cf.b2 = (float)b[2];
  cf.b3 = (float)b[3]; cf.b4 = (float)b[4]; cf.b5 = (float)b[5];
  cf.a1 = (float)a[1]; cf.a2 = (float)a[2]; cf.a3 = (float)a[3];
  cf.a4 = (float)a[4]; cf.a5 = (float)a[5];
  cf.zi0 = (float)zi[0]; cf.zi1 = (float)zi[1]; cf.zi2 = (float)zi[2];
  cf.zi3 = (float)zi[3]; cf.zi4 = (float)zi[4];
  return cf;
}

extern "C" void kernel_launch(void* const* d_in, const int* in_sizes, int n_in,
                              void* d_out, int out_size, void* d_ws, size_t ws_size,
                              hipStream_t stream) {
  const float* x = (const float*)d_in[0];
  float* out = (float*)d_out;

  // workspace layout
  ushort* BT1 = (ushort*)d_ws;                 // 1024*1024 bf16
  ushort* BT2 = BT1 + 1024 * 1024;             // 1024*1024 bf16
  ushort* A1  = BT2 + 1024 * 1024;             // 4096*1024 bf16
  ushort* A2  = A1 + (size_t)NFRAMES * 1024;   // 4096*1024 bf16
  float*  Fr  = (float*)(A2 + (size_t)NFRAMES * 1024);  // 4096*1024 f32 (C1 & C2)
  float*  Sg  = Fr + (size_t)NFRAMES * 1024;   // 64*17150
  float*  Xe  = Sg + NB * TLEN;                // 64*17186
  float*  Y1  = Xe + NB * LXLEN;               // 64*17186
  float*  Ft  = Y1 + NB * LXLEN;               // 64*17150
  size_t need = (size_t)((char*)(Ft + NB * TLEN) - (char*)d_ws);
  if (ws_size < need) return;

  IirCoef cf = make_coef();

  gen_bt1<<<4096, 256, 0, stream>>>(BT1);
  gen_bt2<<<4096, 256, 0, stream>>>(BT2);
  build_a1<<<1024, 256, 0, stream>>>(x, A1);
  gemm_mfma<<<dim3(8, 32), 256, 0, stream>>>(A1, BT1, Fr);
  overlap_add<<<(NB * TLEN + 255) / 256, 256, 0, stream>>>(Fr, Sg);
  build_xe<<<(NB * LXLEN + 255) / 256, 256, 0, stream>>>(Sg, Xe);
  iir_fwd<<<(NB * NCH + 63) / 64, 64, 0, stream>>>(Xe, Y1, cf);
  iir_bwd<<<(NB * NCH + 63) / 64, 64, 0, stream>>>(Y1, Ft, cf);
  build_a2<<<(NFRAMES * 1024 + 255) / 256, 256, 0, stream>>>(Ft, A2);
  gemm_mfma<<<dim3(8, 32), 256, 0, stream>>>(A2, BT2, Fr);
  transpose_out<<<1024, 256, 0, stream>>>(Fr, out);
}

// Round 3
// 132.033 us; speedup vs baseline: 5.3951x; 1.9375x over previous
//
#include <hip/hip_runtime.h>
#include <cmath>
#include <complex>
#include <algorithm>

#define NW      1022
#define NB      64
#define TLEN    17150   /* HOP*(F-1)+W */
#define PADL    18
#define LXLEN   17186   /* TLEN + 2*PADL */
#define NFRAMES 4096    /* NB*64 */
#define CHUNK   64
#define VWARM   64
#define NCH     269     /* ceil(LXLEN/CHUNK) */
#define GK      1024    /* padded K for both GEMMs */

typedef __attribute__((ext_vector_type(8))) short short8;
typedef __attribute__((ext_vector_type(4))) float floatx4;

struct IirCoef {
  float b0,b1,b2,b3,b4,b5;
  float a1,a2,a3,a4,a5;
  float zi0,zi1,zi2,zi3,zi4;
};

static __device__ __forceinline__ ushort f2bf(float f) {
  uint32_t u = __builtin_bit_cast(uint32_t, f);
  uint32_t r = (u + 0x7FFFu + ((u >> 16) & 1u)) >> 16;   // RNE
  return (ushort)r;
}

// fp32-exact (k*t) mod 1022 for k*t < 2^24, then radians in [0, 2pi)
static __device__ __forceinline__ float phase_mod(int k, int t) {
  const float TPN = 6.2831853071795864769f / 1022.f;
  float kt = (float)(k * t);                 // exact: < 2^24
  float q = floorf(kt * (1.0f / 1022.0f));
  float r = kt - q * 1022.0f;
  if (r < 0.f) r += 1022.f;
  if (r >= 1022.f) r -= 1022.f;
  return r * TPN;
}

// ---------------- basis generation (transposed, bf16, padded to 1024) -------
// BT1[n=t][k=kk]: irfft basis * SYN window. Rows t>=1022 are zero.
__global__ void gen_bt1(ushort* __restrict__ BT1) {
  int idx = blockIdx.x * 256 + threadIdx.x;   // 1024*1024
  int t = idx >> 10, kk = idx & 1023;
  int k = kk & 511;
  float val = 0.f;
  if (t < NW) {
    const float TPN = 6.2831853071795864769f / 1022.f;
    float fw = 0.5f - 0.5f * __cosf((float)t * TPN);
    float den = 0.f;
    int tm = t & 255;
    #pragma unroll
    for (int j = 0; j < 4; ++j) {
      int u = tm + (j << 8);
      if (u < NW) { float w = 0.5f - 0.5f * __cosf((float)u * TPN); den += w * w; }
    }
    float syn = fw / den;
    float arg = phase_mod(k, t);
    float scale = (k == 0 || k == 511) ? 1.f : 2.f;
    if (kk < 512) val = __cosf(arg) * scale * (1.f / 1022.f) * syn;
    else          val = (k == 0 || k == 511) ? 0.f
                        : -__sinf(arg) * scale * (1.f / 1022.f) * syn;
  }
  BT1[idx] = f2bf(val);
}

// BT2[n=kk][k=t]: forward rfft basis * FWD window. Cols t>=1022 are zero.
__global__ void gen_bt2(ushort* __restrict__ BT2) {
  int idx = blockIdx.x * 256 + threadIdx.x;   // 1024*1024
  int kk = idx >> 10, t = idx & 1023;
  int k = kk & 511;
  float val = 0.f;
  if (t < NW) {
    const float TPN = 6.2831853071795864769f / 1022.f;
    float fw = 0.5f - 0.5f * __cosf((float)t * TPN);
    float arg = phase_mod(k, t);
    val = (kk < 512) ? fw * __cosf(arg) : -fw * __sinf(arg);
  }
  BT2[idx] = f2bf(val);
}

// ---------------- input transpose: x (b,k,f,ri) -> A1[b*64+f][ri*512+k] bf16
__global__ __launch_bounds__(256) void build_a1(const float* __restrict__ x,
                                                ushort* __restrict__ A1) {
  __shared__ float tile[32][129];
  int b  = blockIdx.x >> 4;
  int k0 = (blockIdx.x & 15) << 5;
  int tid = threadIdx.x;
  #pragma unroll
  for (int e = 0; e < 16; ++e) {
    int lin = tid + e * 256;
    int i = lin >> 7, c = lin & 127;
    tile[i][c] = x[(b * 512 + k0 + i) * 128 + c];
  }
  __syncthreads();
  #pragma unroll
  for (int e = 0; e < 16; ++e) {
    int lin = tid + e * 256;
    int c = lin >> 5, i = lin & 31;
    int f = c >> 1, ri = c & 1;
    A1[(b * 64 + f) * 1024 + ri * 512 + k0 + i] = f2bf(tile[i][c]);
  }
}

// ---------------- bf16 MFMA GEMM: C[4096,1024] = A[4096,GK] * Bt[1024,GK]^T --
// 128x128 tile, BK=64, 4 waves (2x2), wave tile 64x64, read-side XOR swizzle
// (chunk ^= row&7) realized via pre-swizzled global source for global_load_lds.
#define GLOAD16(gsrc, ldst) \
  __builtin_amdgcn_global_load_lds( \
      (const __attribute__((address_space(1))) void*)(gsrc), \
      (__attribute__((address_space(3))) void*)(ldst), 16, 0, 0)

__global__ __launch_bounds__(256) void gemm_mfma(
    const ushort* __restrict__ A, const ushort* __restrict__ Bt,
    float* __restrict__ C) {
  __shared__ __align__(16) ushort As[128 * 64];
  __shared__ __align__(16) ushort Bs[128 * 64];
  const int tid = threadIdx.x;
  const int wid = tid >> 6, lane = tid & 63;
  const int m0 = blockIdx.y * 128, n0 = blockIdx.x * 128;
  const int warp_m = wid >> 1, warp_n = wid & 1;

  floatx4 acc[4][4];
  #pragma unroll
  for (int i = 0; i < 4; ++i)
    #pragma unroll
    for (int j = 0; j < 4; ++j) acc[i][j] = (floatx4){0.f, 0.f, 0.f, 0.f};

  const int lr = lane >> 3;          // 0..7
  const int lc = lane & 7;           // chunk
  const int swz = lc ^ lr;           // inverse-swizzled source chunk
  const ushort* aBase = A  + (size_t)(m0 + wid * 8 + lr) * GK + swz * 8;
  const ushort* bBase = Bt + (size_t)(n0 + wid * 8 + lr) * GK + swz * 8;
  ushort* aDst = As + (wid * 8) * 64;
  ushort* bDst = Bs + (wid * 8) * 64;

  const int lane15 = lane & 15;
  const int g = lane >> 4;           // k-group
  const int rx = lane & 7;           // row&7 for swizzle
  const int arow = warp_m * 64 + lane15;
  const int brow = warp_n * 64 + lane15;

  for (int k0 = 0; k0 < GK; k0 += 64) {
    #pragma unroll
    for (int p = 0; p < 4; ++p) {
      GLOAD16(aBase + (size_t)(p * 32) * GK + k0, aDst + p * 2048);
      GLOAD16(bBase + (size_t)(p * 32) * GK + k0, bDst + p * 2048);
    }
    __syncthreads();
    #pragma unroll
    for (int ks = 0; ks < 2; ++ks) {
      short8 af[4], bfr[4];
      const int chunk = ((ks << 2) + g) ^ rx;
      #pragma unroll
      for (int fm = 0; fm < 4; ++fm)
        af[fm] = *(const short8*)(As + (arow + fm * 16) * 64 + chunk * 8);
      #pragma unroll
      for (int fn = 0; fn < 4; ++fn)
        bfr[fn] = *(const short8*)(Bs + (brow + fn * 16) * 64 + chunk * 8);
      #pragma unroll
      for (int fm = 0; fm < 4; ++fm)
        #pragma unroll
        for (int fn = 0; fn < 4; ++fn)
          acc[fm][fn] = __builtin_amdgcn_mfma_f32_16x16x32_bf16(
              af[fm], bfr[fn], acc[fm][fn], 0, 0, 0);
    }
    __syncthreads();
  }

  #pragma unroll
  for (int fm = 0; fm < 4; ++fm) {
    #pragma unroll
    for (int fn = 0; fn < 4; ++fn) {
      #pragma unroll
      for (int i = 0; i < 4; ++i) {
        int gm = m0 + warp_m * 64 + fm * 16 + g * 4 + i;
        int gn = n0 + warp_n * 64 + fn * 16 + lane15;
        C[(size_t)gm * 1024 + gn] = acc[fm][fn][i];
      }
    }
  }
}

// ---------------- overlap-add (frames stride 1024) ----------------
__global__ void overlap_add(const float* __restrict__ frames, float* __restrict__ s) {
  int idx = blockIdx.x * 256 + threadIdx.x;
  if (idx >= NB * TLEN) return;
  int b = idx / TLEN, tau = idx % TLEN;
  int fhi = tau >> 8;
  int flo = fhi - 3; if (flo < 0) flo = 0;
  if (fhi > 63) fhi = 63;
  float sum = 0.f;
  for (int f = flo; f <= fhi; ++f) {
    int off = tau - (f << 8);
    if (off < NW) sum += frames[(size_t)(b * 64 + f) * 1024 + off];
  }
  s[idx] = sum;
}

// ---------------- reflect-pad on the fly ----------------
static __device__ __forceinline__ float xe_at(const float* __restrict__ sr, int i) {
  if (i < PADL) return 2.f * sr[0] - sr[PADL - i];
  if (i < PADL + TLEN) return sr[i - PADL];
  int j = i - (PADL + TLEN);
  return 2.f * sr[TLEN - 1] - sr[TLEN - 2 - j];
}

// ---------------- IIR (DF2T), chunked with zero-state warm-up ----------------
#define IIR_STEP(x, y)                                   \
  float y = fmaf(cf.b0, (x), z0);                        \
  z0 = fmaf(-cf.a1, y, fmaf(cf.b1, (x), z1));            \
  z1 = fmaf(-cf.a2, y, fmaf(cf.b2, (x), z2));            \
  z2 = fmaf(-cf.a3, y, fmaf(cf.b3, (x), z3));            \
  z3 = fmaf(-cf.a4, y, fmaf(cf.b4, (x), z4));            \
  z4 = fmaf(-cf.a5, y, cf.b5 * (x));

__global__ __launch_bounds__(64) void iir_fwd(const float* __restrict__ s,
                                              float* __restrict__ y1, IirCoef cf) {
  int task = blockIdx.x * 64 + threadIdx.x;
  if (task >= NB * NCH) return;
  int row = task / NCH, ch = task % NCH;
  const float* sr = s + row * TLEN;
  float* yr = y1 + row * LXLEN;
  float z0, z1, z2, z3, z4;
  int start = ch * CHUNK;
  int i;
  if (ch == 0) {
    float x0 = xe_at(sr, 0);
    z0 = cf.zi0 * x0; z1 = cf.zi1 * x0; z2 = cf.zi2 * x0;
    z3 = cf.zi3 * x0; z4 = cf.zi4 * x0;
    i = 0;
  } else {
    z0 = z1 = z2 = z3 = z4 = 0.f;
    i = start - VWARM;
    #pragma unroll 4
    for (; i < start; ++i) { float x = xe_at(sr, i); IIR_STEP(x, y); (void)y; }
  }
  int end = start + CHUNK; if (end > LXLEN) end = LXLEN;
  #pragma unroll 4
  for (; i < end; ++i) {
    float x = xe_at(sr, i);
    IIR_STEP(x, y);
    yr[i] = y;
  }
}

__global__ __launch_bounds__(64) void iir_bwd(const float* __restrict__ y1,
                                              float* __restrict__ filt, IirCoef cf) {
  int task = blockIdx.x * 64 + threadIdx.x;
  if (task >= NB * NCH) return;
  int row = task / NCH, ch = task % NCH;
  const float* yr = y1 + row * LXLEN;
  float* fr = filt + row * TLEN;
  float z0, z1, z2, z3, z4;
  int start = ch * CHUNK;
  int i;
  if (ch == 0) {
    float x0 = yr[LXLEN - 1];
    z0 = cf.zi0 * x0; z1 = cf.zi1 * x0; z2 = cf.zi2 * x0;
    z3 = cf.zi3 * x0; z4 = cf.zi4 * x0;
    i = 0;
  } else {
    z0 = z1 = z2 = z3 = z4 = 0.f;
    i = start - VWARM;
    #pragma unroll 4
    for (; i < start; ++i) { float x = yr[LXLEN - 1 - i]; IIR_STEP(x, y); (void)y; }
  }
  int end = start + CHUNK; if (end > LXLEN) end = LXLEN;
  #pragma unroll 4
  for (; i < end; ++i) {
    float x = yr[LXLEN - 1 - i];
    IIR_STEP(x, y);
    if (i >= PADL && i < PADL + TLEN) fr[(PADL + TLEN - 1) - i] = y;
  }
}

// ---------------- frame gather -> bf16 A2 (K padded to 1024) ----------------
__global__ void build_a2(const float* __restrict__ filt, ushort* __restrict__ A2) {
  int idx = blockIdx.x * 256 + threadIdx.x;
  if (idx >= NFRAMES * 1024) return;
  int fid = idx >> 10, t = idx & 1023;
  int b = fid >> 6, f = fid & 63;
  float v = (t < NW) ? filt[b * TLEN + (f << 8) + t] : 0.f;
  A2[idx] = f2bf(v);
}

// ---------------- output transpose: Out2[fid][ri*512+k] -> out[b][k][f][ri] --
__global__ __launch_bounds__(256) void transpose_out(const float* __restrict__ Out2,
                                                     float* __restrict__ out) {
  __shared__ float tile[128][33];
  int b  = blockIdx.x >> 4;
  int k0 = (blockIdx.x & 15) << 5;
  int tid = threadIdx.x;
  #pragma unroll
  for (int e = 0; e < 16; ++e) {
    int lin = tid + e * 256;
    int c = lin >> 5, i = lin & 31;
    int f = c >> 1, ri = c & 1;
    tile[c][i] = Out2[(size_t)(b * 64 + f) * 1024 + ri * 512 + k0 + i];
  }
  __syncthreads();
  #pragma unroll
  for (int e = 0; e < 16; ++e) {
    int lin = tid + e * 256;
    int i = lin >> 7, c = lin & 127;
    out[(b * 512 + k0 + i) * 128 + c] = tile[c][i];
  }
}

// ---------------- host: butter(5,0.5) + lfilter_zi ----------------
static void solve5(double M[5][5], double v[5], double outv[5]) {
  for (int col = 0; col < 5; ++col) {
    int piv = col;
    for (int r = col + 1; r < 5; ++r)
      if (std::fabs(M[r][col]) > std::fabs(M[piv][col])) piv = r;
    if (piv != col) {
      for (int c = 0; c < 5; ++c) std::swap(M[col][c], M[piv][c]);
      std::swap(v[col], v[piv]);
    }
    double d = M[col][col];
    for (int r = col + 1; r < 5; ++r) {
      double f = M[r][col] / d;
      for (int c = col; c < 5; ++c) M[r][c] -= f * M[col][c];
      v[r] -= f * v[col];
    }
  }
  for (int r = 4; r >= 0; --r) {
    double s = v[r];
    for (int c = r + 1; c < 5; ++c) s -= M[r][c] * outv[c];
    outv[r] = s / M[r][r];
  }
}

static IirCoef make_coef() {
  const double PI = 3.14159265358979323846;
  std::complex<double> p[5];
  for (int i = 0; i < 5; ++i) {
    double m = -4.0 + 2.0 * i;
    p[i] = -std::exp(std::complex<double>(0.0, PI * m / 10.0));
  }
  double fs = 2.0;
  double warped = 2.0 * fs * std::tan(PI * 0.5 / fs);
  for (int i = 0; i < 5; ++i) p[i] *= warped;
  double kgain = std::pow(warped, 5.0);
  double fs2 = 2.0 * fs;
  std::complex<double> pd[5], prod(1.0, 0.0);
  for (int i = 0; i < 5; ++i) {
    pd[i] = (fs2 + p[i]) / (fs2 - p[i]);
    prod *= (fs2 - p[i]);
  }
  double kd = kgain * std::real(1.0 / prod);
  double b[6] = {kd, 5 * kd, 10 * kd, 10 * kd, 5 * kd, kd};
  std::complex<double> c[6] = {{1,0},{0,0},{0,0},{0,0},{0,0},{0,0}};
  for (int i = 0; i < 5; ++i)
    for (int j = i + 1; j >= 1; --j)
      c[j] -= pd[i] * c[j - 1];
  double a[6]; for (int i = 0; i < 6; ++i) a[i] = c[i].real();
  double M[5][5], v[5];
  for (int r = 0; r < 5; ++r)
    for (int cc = 0; cc < 5; ++cc) {
      double Af = 0.0;
      if (cc == 0) Af = -a[r + 1];
      if (cc == r + 1) Af = 1.0;
      M[r][cc] = (r == cc ? 1.0 : 0.0) - Af;
    }
  for (int r = 0; r < 5; ++r) v[r] = b[r + 1] - a[r + 1] * b[0];
  double zi[5];
  solve5(M, v, zi);
  IirCoef cf;
  cf.b0 = (float)b[0]; cf.b1 = (float)b[1]; cf.b2 = (float)b[2];
  cf.b3 = (float)b[3]; cf.b4 = (float)b[4]; cf.b5 = (float)b[5];
  cf.a1 = (float)a[1]; cf.a2 = (float)a[2]; cf.a3 = (float)a[3];
  cf.a4 = (float)a[4]; cf.a5 = (float)a[5];
  cf.zi0 = (float)zi[0]; cf.zi1 = (float)zi[1]; cf.zi2 = (float)zi[2];
  cf.zi3 = (float)zi[3]; cf.zi4 = (float)zi[4];
  return cf;
}

extern "C" void kernel_launch(void* const* d_in, const int* in_sizes, int n_in,
                              void* d_out, int out_size, void* d_ws, size_t ws_size,
                              hipStream_t stream) {
  const float* x = (const float*)d_in[0];
  float* out = (float*)d_out;

  // workspace layout
  ushort* BT1 = (ushort*)d_ws;                 // 1024*1024 bf16
  ushort* BT2 = BT1 + 1024 * 1024;             // 1024*1024 bf16
  ushort* A1  = BT2 + 1024 * 1024;             // 4096*1024 bf16
  ushort* A2  = A1 + (size_t)NFRAMES * 1024;   // 4096*1024 bf16
  float*  Fr  = (float*)(A2 + (size_t)NFRAMES * 1024);  // 4096*1024 f32 (C1 & C2)
  float*  Sg  = Fr + (size_t)NFRAMES * 1024;   // 64*17150
  float*  Y1  = Sg + NB * TLEN;                // 64*17186
  float*  Ft  = Y1 + NB * LXLEN;               // 64*17150
  size_t need = (size_t)((char*)(Ft + NB * TLEN) - (char*)d_ws);
  if (ws_size < need) return;

  IirCoef cf = make_coef();

  gen_bt1<<<4096, 256, 0, stream>>>(BT1);
  gen_bt2<<<4096, 256, 0, stream>>>(BT2);
  build_a1<<<1024, 256, 0, stream>>>(x, A1);
  gemm_mfma<<<dim3(8, 32), 256, 0, stream>>>(A1, BT1, Fr);
  overlap_add<<<(NB * TLEN + 255) / 256, 256, 0, stream>>>(Fr, Sg);
  iir_fwd<<<(NB * NCH + 63) / 64, 64, 0, stream>>>(Sg, Y1, cf);
  iir_bwd<<<(NB * NCH + 63) / 64, 64, 0, stream>>>(Y1, Ft, cf);
  build_a2<<<(NFRAMES * 1024 + 255) / 256, 256, 0, stream>>>(Ft, A2);
  gemm_mfma<<<dim3(8, 32), 256, 0, stream>>>(A2, BT2, Fr);
  transpose_out<<<1024, 256, 0, stream>>>(Fr, out);
}

// Round 4
// 104.988 us; speedup vs baseline: 6.7849x; 1.2576x over previous
//
#include <hip/hip_runtime.h>
#include <cmath>
#include <complex>
#include <algorithm>

#define NW      1022
#define NB      64
#define TLEN    17150   /* HOP*(F-1)+W */
#define PADL    18
#define LXLEN   17186   /* TLEN + 2*PADL */
#define NFRAMES 4096    /* NB*64 */
#define GK      1024    /* padded K for both GEMMs */
#define BS      4288    /* samples per oa_iir split (4 splits/row) */
#define SPAN    4480    /* LDS floats per buffer in oa_iir */

typedef __attribute__((ext_vector_type(8))) short short8;
typedef __attribute__((ext_vector_type(4))) float floatx4;

struct IirCoef {
  float b0,b1,b2,b3,b4,b5;
  float a1,a2,a3,a4,a5;
  float zi0,zi1,zi2,zi3,zi4;
};

static __device__ __forceinline__ ushort f2bf(float f) {
  uint32_t u = __builtin_bit_cast(uint32_t, f);
  uint32_t r = (u + 0x7FFFu + ((u >> 16) & 1u)) >> 16;   // RNE
  return (ushort)r;
}

// fp32-exact (k*t) mod 1022 for k*t < 2^24, then radians in [0, 2pi)
static __device__ __forceinline__ float phase_mod(int k, int t) {
  const float TPN = 6.2831853071795864769f / 1022.f;
  float kt = (float)(k * t);                 // exact: < 2^24
  float q = floorf(kt * (1.0f / 1022.0f));
  float r = kt - q * 1022.0f;
  if (r < 0.f) r += 1022.f;
  if (r >= 1022.f) r -= 1022.f;
  return r * TPN;
}

// ---------------- basis generation (transposed, bf16, padded to 1024) -------
__global__ void gen_bt1(ushort* __restrict__ BT1) {
  int idx = blockIdx.x * 256 + threadIdx.x;   // 1024*1024
  int t = idx >> 10, kk = idx & 1023;
  int k = kk & 511;
  float val = 0.f;
  if (t < NW) {
    const float TPN = 6.2831853071795864769f / 1022.f;
    float fw = 0.5f - 0.5f * __cosf((float)t * TPN);
    float den = 0.f;
    int tm = t & 255;
    #pragma unroll
    for (int j = 0; j < 4; ++j) {
      int u = tm + (j << 8);
      if (u < NW) { float w = 0.5f - 0.5f * __cosf((float)u * TPN); den += w * w; }
    }
    float syn = fw / den;
    float arg = phase_mod(k, t);
    float scale = (k == 0 || k == 511) ? 1.f : 2.f;
    if (kk < 512) val = __cosf(arg) * scale * (1.f / 1022.f) * syn;
    else          val = (k == 0 || k == 511) ? 0.f
                        : -__sinf(arg) * scale * (1.f / 1022.f) * syn;
  }
  BT1[idx] = f2bf(val);
}

__global__ void gen_bt2(ushort* __restrict__ BT2) {
  int idx = blockIdx.x * 256 + threadIdx.x;   // 1024*1024
  int kk = idx >> 10, t = idx & 1023;
  int k = kk & 511;
  float val = 0.f;
  if (t < NW) {
    const float TPN = 6.2831853071795864769f / 1022.f;
    float fw = 0.5f - 0.5f * __cosf((float)t * TPN);
    float arg = phase_mod(k, t);
    val = (kk < 512) ? fw * __cosf(arg) : -fw * __sinf(arg);
  }
  BT2[idx] = f2bf(val);
}

// ---------------- input transpose: x (b,k,f,ri) -> A1[b*64+f][ri*512+k] bf16
__global__ __launch_bounds__(256) void build_a1(const float* __restrict__ x,
                                                ushort* __restrict__ A1) {
  __shared__ float tile[32][129];
  int b  = blockIdx.x >> 4;
  int k0 = (blockIdx.x & 15) << 5;
  int tid = threadIdx.x;
  #pragma unroll
  for (int e = 0; e < 16; ++e) {
    int lin = tid + e * 256;
    int i = lin >> 7, c = lin & 127;
    tile[i][c] = x[(b * 512 + k0 + i) * 128 + c];
  }
  __syncthreads();
  #pragma unroll
  for (int e = 0; e < 16; ++e) {
    int lin = tid + e * 256;
    int c = lin >> 5, i = lin & 31;
    int f = c >> 1, ri = c & 1;
    A1[(b * 64 + f) * 1024 + ri * 512 + k0 + i] = f2bf(tile[i][c]);
  }
}

// ---------------- shared GEMM pieces ----------------
#define GLOAD16(gsrc, ldst) \
  __builtin_amdgcn_global_load_lds( \
      (const __attribute__((address_space(1))) void*)(gsrc), \
      (__attribute__((address_space(3))) void*)(ldst), 16, 0, 0)

#define WAIT_VMCNT8()  __builtin_amdgcn_s_waitcnt(0xF78)  /* vmcnt(8), lgkm/exp no-op */
#define WAIT_VMCNT0()  __builtin_amdgcn_s_waitcnt(0xF70)  /* vmcnt(0) */

static __device__ __forceinline__ void gemm_compute(
    const ushort* as, const ushort* bs, int arow, int brow, int g, int rx,
    floatx4 (&acc)[4][4]) {
  #pragma unroll
  for (int ks = 0; ks < 2; ++ks) {
    short8 af[4], bfr[4];
    const int chunk = ((ks << 2) + g) ^ rx;
    #pragma unroll
    for (int fm = 0; fm < 4; ++fm)
      af[fm] = *(const short8*)(as + (arow + fm * 16) * 64 + chunk * 8);
    #pragma unroll
    for (int fn = 0; fn < 4; ++fn)
      bfr[fn] = *(const short8*)(bs + (brow + fn * 16) * 64 + chunk * 8);
    #pragma unroll
    for (int fm = 0; fm < 4; ++fm)
      #pragma unroll
      for (int fn = 0; fn < 4; ++fn)
        acc[fm][fn] = __builtin_amdgcn_mfma_f32_16x16x32_bf16(
            af[fm], bfr[fn], acc[fm][fn], 0, 0, 0);
  }
}

// ---------------- GEMM1: C[4096,1024] = A1 * BT1^T, 2-phase dbuf ----------
__global__ __launch_bounds__(256) void gemm1(
    const ushort* __restrict__ A, const ushort* __restrict__ Bt,
    float* __restrict__ C) {
  __shared__ __align__(16) ushort As[2][128 * 64];
  __shared__ __align__(16) ushort Bs[2][128 * 64];
  const int tid = threadIdx.x;
  const int wid = tid >> 6, lane = tid & 63;
  const int m0 = blockIdx.y * 128, n0 = blockIdx.x * 128;
  const int warp_m = wid >> 1, warp_n = wid & 1;

  floatx4 acc[4][4];
  #pragma unroll
  for (int i = 0; i < 4; ++i)
    #pragma unroll
    for (int j = 0; j < 4; ++j) acc[i][j] = (floatx4){0.f, 0.f, 0.f, 0.f};

  const int lr = lane >> 3, lc = lane & 7;
  const int swz = lc ^ lr;
  const ushort* aBase = A  + (size_t)(m0 + wid * 8 + lr) * GK + swz * 8;
  const ushort* bBase = Bt + (size_t)(n0 + wid * 8 + lr) * GK + swz * 8;

  const int lane15 = lane & 15;
  const int g = lane >> 4;
  const int rx = lane & 7;
  const int arow = warp_m * 64 + lane15;
  const int brow = warp_n * 64 + lane15;

#define STAGE_G1(buf, kk0) do { \
    _Pragma("unroll") \
    for (int p = 0; p < 4; ++p) { \
      GLOAD16(aBase + (size_t)(p * 32) * GK + (kk0), &As[buf][(p * 32 + wid * 8) * 64]); \
      GLOAD16(bBase + (size_t)(p * 32) * GK + (kk0), &Bs[buf][(p * 32 + wid * 8) * 64]); \
    } } while (0)

  STAGE_G1(0, 0);
  for (int t = 0; t < 15; ++t) {
    STAGE_G1((t + 1) & 1, (t + 1) * 64);
    WAIT_VMCNT8();
    __builtin_amdgcn_s_barrier();
    __builtin_amdgcn_sched_barrier(0);
    gemm_compute(&As[t & 1][0], &Bs[t & 1][0], arow, brow, g, rx, acc);
    __builtin_amdgcn_sched_barrier(0);
    __builtin_amdgcn_s_barrier();
  }
  WAIT_VMCNT0();
  __builtin_amdgcn_s_barrier();
  gemm_compute(&As[1][0], &Bs[1][0], arow, brow, g, rx, acc);

  #pragma unroll
  for (int fm = 0; fm < 4; ++fm)
    #pragma unroll
    for (int fn = 0; fn < 4; ++fn)
      #pragma unroll
      for (int i = 0; i < 4; ++i) {
        int gm = m0 + warp_m * 64 + fm * 16 + g * 4 + i;
        int gn = n0 + warp_n * 64 + fn * 16 + lane15;
        C[(size_t)gm * 1024 + gn] = acc[fm][fn][i];
      }
#undef STAGE_G1
}

// ---- GEMM2: out = gather(Ftb) * BT2^T with permuted-B + scatter epilogue ---
// n-slot s in [0,128): kk = bx*64 + (s&63) + (s>>6)*512  (ri = s>>6 = warp_n)
__global__ __launch_bounds__(256) void gemm2(
    const ushort* __restrict__ Ftb, const ushort* __restrict__ Bt,
    float* __restrict__ out) {
  __shared__ __align__(16) ushort As[2][128 * 64];
  __shared__ __align__(16) ushort Bs[2][128 * 64];
  const int tid = threadIdx.x;
  const int wid = tid >> 6, lane = tid & 63;
  const int m0 = blockIdx.y * 128, bx = blockIdx.x;
  const int warp_m = wid >> 1, warp_n = wid & 1;

  floatx4 acc[4][4];
  #pragma unroll
  for (int i = 0; i < 4; ++i)
    #pragma unroll
    for (int j = 0; j < 4; ++j) acc[i][j] = (floatx4){0.f, 0.f, 0.f, 0.f};

  const int lr = lane >> 3, lc = lane & 7;
  const int swz = lc ^ lr;

  // A: gather rows from the bf16 signal buffer: fid -> b*TLEN + f*256
  const ushort* aB[4];
  #pragma unroll
  for (int p = 0; p < 4; ++p) {
    int row_p = m0 + p * 32 + wid * 8 + lr;
    aB[p] = Ftb + (size_t)(row_p >> 6) * TLEN + (row_p & 63) * 256 + swz * 8;
  }
  // B: permuted rows (p<2 -> ri=0 half, p>=2 -> ri=1 half)
  const ushort* bB0 = Bt + (size_t)(bx * 64 + wid * 8 + lr) * GK + swz * 8;

  const int lane15 = lane & 15;
  const int g = lane >> 4;
  const int rx = lane & 7;
  const int arow = warp_m * 64 + lane15;
  const int brow = warp_n * 64 + lane15;

#define STAGE_G2(buf, kk0) do { \
    _Pragma("unroll") \
    for (int p = 0; p < 4; ++p) { \
      GLOAD16(aB[p] + (kk0), &As[buf][(p * 32 + wid * 8) * 64]); \
      size_t boff = (size_t)((p & 1) * 32 + (p >> 1) * 512) * GK; \
      GLOAD16(bB0 + boff + (kk0), &Bs[buf][(((p >> 1) * 64 + (p & 1) * 32) + wid * 8) * 64]); \
    } } while (0)

  STAGE_G2(0, 0);
  for (int t = 0; t < 15; ++t) {
    STAGE_G2((t + 1) & 1, (t + 1) * 64);
    WAIT_VMCNT8();
    __builtin_amdgcn_s_barrier();
    __builtin_amdgcn_sched_barrier(0);
    gemm_compute(&As[t & 1][0], &Bs[t & 1][0], arow, brow, g, rx, acc);
    __builtin_amdgcn_sched_barrier(0);
    __builtin_amdgcn_s_barrier();
  }
  WAIT_VMCNT0();
  __builtin_amdgcn_s_barrier();
  gemm_compute(&As[1][0], &Bs[1][0], arow, brow, g, rx, acc);

  // scatter epilogue: out[((b*512 + k)*64 + f)*2 + ri]
  #pragma unroll
  for (int fm = 0; fm < 4; ++fm)
    #pragma unroll
    for (int fn = 0; fn < 4; ++fn)
      #pragma unroll
      for (int i = 0; i < 4; ++i) {
        int gm = m0 + warp_m * 64 + fm * 16 + g * 4 + i;      // fid
        int s  = warp_n * 64 + fn * 16 + lane15;              // n-slot
        int ri = s >> 6;
        int k  = bx * 64 + (s & 63);
        int bb = gm >> 6, f = gm & 63;
        out[((size_t)(bb * 512 + k)) * 128 + f * 2 + ri] = acc[fm][fn][i];
      }
#undef STAGE_G2
}

// ---------------- fused overlap-add + filtfilt -> bf16 signal ----------------
#define SWZ(r) ((r) ^ (((r) >> 6) & 31))

static __device__ __forceinline__ float oa_sample(const float* __restrict__ frb,
                                                  int tau) {
  int fhi = tau >> 8;
  int flo = fhi - 3; if (flo < 0) flo = 0;
  if (fhi > 63) fhi = 63;
  float sum = 0.f;
  for (int f = flo; f <= fhi; ++f) {
    int off = tau - (f << 8);
    if (off < NW) sum += frb[(size_t)f * 1024 + off];
  }
  return sum;
}

#define IIR_STEP(x, y)                                   \
  float y = fmaf(cf.b0, (x), z0);                        \
  z0 = fmaf(-cf.a1, y, fmaf(cf.b1, (x), z1));            \
  z1 = fmaf(-cf.a2, y, fmaf(cf.b2, (x), z2));            \
  z2 = fmaf(-cf.a3, y, fmaf(cf.b3, (x), z3));            \
  z3 = fmaf(-cf.a4, y, fmaf(cf.b4, (x), z4));            \
  z4 = fmaf(-cf.a5, y, cf.b5 * (x));

__global__ __launch_bounds__(256) void oa_iir(const float* __restrict__ Fr,
                                              ushort* __restrict__ Ftb,
                                              IirCoef cf) {
  __shared__ float bufX[SPAN];   // xe, later y2
  __shared__ float bufY[SPAN];   // y1
  const int blk = blockIdx.x;
  const int b = blk >> 2, sp = blk & 3;
  const int lo = sp * BS;
  const int hi = (lo + BS < TLEN) ? lo + BS : TLEN;     // filt range [lo,hi)
  const int F0 = (sp == 0) ? 0 : lo + PADL;             // fwd output xe-range
  int F1 = hi + PADL + 128; if (F1 > LXLEN) F1 = LXLEN;
  const int XB = (sp == 0) ? 0 : F0 - 64;               // xe LDS base
  const int xspan = F1 - XB;                            // <= SPAN
  const float* frb = Fr + (size_t)b * 64 * 1024;

  // phase 1: xe -> bufX (reflect-pad over overlap-add, computed on the fly)
  for (int rel = threadIdx.x; rel < xspan; rel += 256) {
    int p = XB + rel;
    float v;
    if (p < PADL)                 v = 2.f * oa_sample(frb, 0) - oa_sample(frb, PADL - p);
    else if (p < PADL + TLEN)     v = oa_sample(frb, p - PADL);
    else { int j = p - (PADL + TLEN);
           v = 2.f * oa_sample(frb, TLEN - 1) - oa_sample(frb, TLEN - 2 - j); }
    bufX[SWZ(rel)] = v;
  }
  __syncthreads();

  // phase 2: forward IIR chunks (64 warm + 64 live), bufX -> bufY
  {
    int nch = (F1 - F0 + 63) >> 6;
    int c = threadIdx.x;
    if (c < nch) {
      int os = F0 + (c << 6);
      int oe = os + 64; if (oe > F1) oe = F1;
      float z0, z1, z2, z3, z4;
      int i;
      if (sp == 0 && c == 0) {
        float x0 = bufX[SWZ(0)];
        z0 = cf.zi0 * x0; z1 = cf.zi1 * x0; z2 = cf.zi2 * x0;
        z3 = cf.zi3 * x0; z4 = cf.zi4 * x0;
        i = 0;
      } else {
        z0 = z1 = z2 = z3 = z4 = 0.f;
        i = os - 64;
        #pragma unroll 4
        for (; i < os; ++i) { float x = bufX[SWZ(i - XB)]; IIR_STEP(x, y); (void)y; }
      }
      #pragma unroll 4
      for (; i < oe; ++i) {
        float x = bufX[SWZ(i - XB)];
        IIR_STEP(x, y);
        bufY[SWZ(i - XB)] = y;
      }
    }
  }
  __syncthreads();

  // phase 3: backward IIR chunks (absolute 64-aligned reversed grid), bufY -> bufX
  {
    const int R0 = TLEN + PADL - hi;          // owned reversed range [R0, R1)
    const int R1 = LXLEN - lo - PADL;
    int k_lo = R0 >> 6, k_hi = (R1 - 1) >> 6;
    int k = k_lo + threadIdx.x;
    if (k <= k_hi) {
      int rs = k << 6;
      int re = rs + 64; if (re > R1) re = R1;
      float z0, z1, z2, z3, z4;
      int i;
      if (k == 0) {
        float x0 = bufY[SWZ(LXLEN - 1 - XB)];
        z0 = cf.zi0 * x0; z1 = cf.zi1 * x0; z2 = cf.zi2 * x0;
        z3 = cf.zi3 * x0; z4 = cf.zi4 * x0;
        i = 0;
      } else {
        z0 = z1 = z2 = z3 = z4 = 0.f;
        i = rs - 64;
        #pragma unroll 4
        for (; i < rs; ++i) { float x = bufY[SWZ(LXLEN - 1 - i - XB)]; IIR_STEP(x, y); (void)y; }
      }
      #pragma unroll 4
      for (; i < re; ++i) {
        float x = bufY[SWZ(LXLEN - 1 - i - XB)];
        IIR_STEP(x, y);
        if (i >= R0) bufX[SWZ(LXLEN - 1 - i - XB)] = y;
      }
    }
  }
  __syncthreads();

  // phase 4: coalesced bf16 write of owned filt range
  for (int t = lo + threadIdx.x; t < hi; t += 256)
    Ftb[(size_t)b * TLEN + t] = f2bf(bufX[SWZ(t + PADL - XB)]);
  // zero-pad tail so gemm2's K-padding reads stay finite
  if (b == NB - 1 && sp == 3)
    for (int t = threadIdx.x; t < 1024; t += 256)
      Ftb[(size_t)NB * TLEN + t] = 0;
}

// ---------------- host: butter(5,0.5) + lfilter_zi ----------------
static void solve5(double M[5][5], double v[5], double outv[5]) {
  for (int col = 0; col < 5; ++col) {
    int piv = col;
    for (int r = col + 1; r < 5; ++r)
      if (std::fabs(M[r][col]) > std::fabs(M[piv][col])) piv = r;
    if (piv != col) {
      for (int c = 0; c < 5; ++c) std::swap(M[col][c], M[piv][c]);
      std::swap(v[col], v[piv]);
    }
    double d = M[col][col];
    for (int r = col + 1; r < 5; ++r) {
      double f = M[r][col] / d;
      for (int c = col; c < 5; ++c) M[r][c] -= f * M[col][c];
      v[r] -= f * v[col];
    }
  }
  for (int r = 4; r >= 0; --r) {
    double s = v[r];
    for (int c = r + 1; c < 5; ++c) s -= M[r][c] * outv[c];
    outv[r] = s / M[r][r];
  }
}

static IirCoef make_coef() {
  const double PI = 3.14159265358979323846;
  std::complex<double> p[5];
  for (int i = 0; i < 5; ++i) {
    double m = -4.0 + 2.0 * i;
    p[i] = -std::exp(std::complex<double>(0.0, PI * m / 10.0));
  }
  double fs = 2.0;
  double warped = 2.0 * fs * std::tan(PI * 0.5 / fs);
  for (int i = 0; i < 5; ++i) p[i] *= warped;
  double kgain = std::pow(warped, 5.0);
  double fs2 = 2.0 * fs;
  std::complex<double> pd[5], prod(1.0, 0.0);
  for (int i = 0; i < 5; ++i) {
    pd[i] = (fs2 + p[i]) / (fs2 - p[i]);
    prod *= (fs2 - p[i]);
  }
  double kd = kgain * std::real(1.0 / prod);
  double b[6] = {kd, 5 * kd, 10 * kd, 10 * kd, 5 * kd, kd};
  std::complex<double> c[6] = {{1,0},{0,0},{0,0},{0,0},{0,0},{0,0}};
  for (int i = 0; i < 5; ++i)
    for (int j = i + 1; j >= 1; --j)
      c[j] -= pd[i] * c[j - 1];
  double a[6]; for (int i = 0; i < 6; ++i) a[i] = c[i].real();
  double M[5][5], v[5];
  for (int r = 0; r < 5; ++r)
    for (int cc = 0; cc < 5; ++cc) {
      double Af = 0.0;
      if (cc == 0) Af = -a[r + 1];
      if (cc == r + 1) Af = 1.0;
      M[r][cc] = (r == cc ? 1.0 : 0.0) - Af;
    }
  for (int r = 0; r < 5; ++r) v[r] = b[r + 1] - a[r + 1] * b[0];
  double zi[5];
  solve5(M, v, zi);
  IirCoef cf;
  cf.b0 = (float)b[0]; cf.b1 = (float)b[1]; cf.b2 = (float)b[2];
  cf.b3 = (float)b[3]; cf.b4 = (float)b[4]; cf.b5 = (float)b[5];
  cf.a1 = (float)a[1]; cf.a2 = (float)a[2]; cf.a3 = (float)a[3];
  cf.a4 = (float)a[4]; cf.a5 = (float)a[5];
  cf.zi0 = (float)zi[0]; cf.zi1 = (float)zi[1]; cf.zi2 = (float)zi[2];
  cf.zi3 = (float)zi[3]; cf.zi4 = (float)zi[4];
  return cf;
}

extern "C" void kernel_launch(void* const* d_in, const int* in_sizes, int n_in,
                              void* d_out, int out_size, void* d_ws, size_t ws_size,
                              hipStream_t stream) {
  const float* x = (const float*)d_in[0];
  float* out = (float*)d_out;

  // workspace layout
  ushort* BT1 = (ushort*)d_ws;                   // 1024*1024 bf16
  ushort* BT2 = BT1 + 1024 * 1024;               // 1024*1024 bf16
  ushort* A1  = BT2 + 1024 * 1024;               // 4096*1024 bf16
  ushort* Ftb = A1 + (size_t)NFRAMES * 1024;     // NB*TLEN + 1024 bf16
  float*  Fr  = (float*)(Ftb + (size_t)NB * TLEN + 1024);  // 4096*1024 f32
  size_t need = (size_t)((char*)(Fr + (size_t)NFRAMES * 1024) - (char*)d_ws);
  if (ws_size < need) return;

  IirCoef cf = make_coef();

  gen_bt1<<<4096, 256, 0, stream>>>(BT1);
  gen_bt2<<<4096, 256, 0, stream>>>(BT2);
  build_a1<<<1024, 256, 0, stream>>>(x, A1);
  gemm1<<<dim3(8, 32), 256, 0, stream>>>(A1, BT1, Fr);
  oa_iir<<<NB * 4, 256, 0, stream>>>(Fr, Ftb, cf);
  gemm2<<<dim3(8, 32), 256, 0, stream>>>(Ftb, BT2, out);
}

// Round 5
// 82.870 us; speedup vs baseline: 8.5958x; 1.2669x over previous
//
#include <hip/hip_runtime.h>
#include <cmath>
#include <complex>
#include <algorithm>

#define NW      1022
#define NB      64
#define TLEN    17150   /* HOP*(F-1)+W */
#define PADL    18
#define LXLEN   17186   /* TLEN + 2*PADL */
#define NFRAMES 4096    /* NB*64 */
#define GK      1024    /* padded K for both GEMMs */
#define BS      4288    /* samples per oa_iir split (4 splits/row) */
#define SPAN    4480    /* LDS floats per buffer in oa_iir */

typedef __attribute__((ext_vector_type(8))) short short8;
typedef __attribute__((ext_vector_type(4))) float floatx4;

struct IirCoef {
  float b0,b1,b2,b3,b4,b5;
  float a1,a2,a3,a4,a5;
  float zi0,zi1,zi2,zi3,zi4;
};

static __device__ __forceinline__ ushort f2bf(float f) {
  uint32_t u = __builtin_bit_cast(uint32_t, f);
  uint32_t r = (u + 0x7FFFu + ((u >> 16) & 1u)) >> 16;   // RNE
  return (ushort)r;
}

// fp32-exact (k*t) mod 1022 for k*t < 2^24, then radians in [0, 2pi)
static __device__ __forceinline__ float phase_mod(int k, int t) {
  const float TPN = 6.2831853071795864769f / 1022.f;
  float kt = (float)(k * t);                 // exact: < 2^24
  float q = floorf(kt * (1.0f / 1022.0f));
  float r = kt - q * 1022.0f;
  if (r < 0.f) r += 1022.f;
  if (r >= 1022.f) r -= 1022.f;
  return r * TPN;
}

// ---------------- fused prep: BT1 | BT2 | A1-transpose ----------------
// blocks [0,4096): BT1; [4096,8192): BT2; [8192,9216): build_a1 tiles
__global__ __launch_bounds__(256) void prep(const float* __restrict__ x,
                                            ushort* __restrict__ BT1,
                                            ushort* __restrict__ BT2,
                                            ushort* __restrict__ A1) {
  __shared__ float tile[32][129];
  int bid = blockIdx.x;
  if (bid < 4096) {
    int idx = bid * 256 + threadIdx.x;        // BT1[t][kk]
    int t = idx >> 10, kk = idx & 1023;
    int k = kk & 511;
    float val = 0.f;
    if (t < NW) {
      const float TPN = 6.2831853071795864769f / 1022.f;
      float fw = 0.5f - 0.5f * __cosf((float)t * TPN);
      float den = 0.f;
      int tm = t & 255;
      #pragma unroll
      for (int j = 0; j < 4; ++j) {
        int u = tm + (j << 8);
        if (u < NW) { float w = 0.5f - 0.5f * __cosf((float)u * TPN); den += w * w; }
      }
      float syn = fw / den;
      float arg = phase_mod(k, t);
      float scale = (k == 0 || k == 511) ? 1.f : 2.f;
      if (kk < 512) val = __cosf(arg) * scale * (1.f / 1022.f) * syn;
      else          val = (k == 0 || k == 511) ? 0.f
                          : -__sinf(arg) * scale * (1.f / 1022.f) * syn;
    }
    BT1[idx] = f2bf(val);
  } else if (bid < 8192) {
    int idx = (bid - 4096) * 256 + threadIdx.x;  // BT2[kk][t]
    int kk = idx >> 10, t = idx & 1023;
    int k = kk & 511;
    float val = 0.f;
    if (t < NW) {
      const float TPN = 6.2831853071795864769f / 1022.f;
      float fw = 0.5f - 0.5f * __cosf((float)t * TPN);
      float arg = phase_mod(k, t);
      val = (kk < 512) ? fw * __cosf(arg) : -fw * __sinf(arg);
    }
    BT2[idx] = f2bf(val);
  } else {
    int tb = bid - 8192;
    int b  = tb >> 4;
    int k0 = (tb & 15) << 5;
    int tid = threadIdx.x;
    #pragma unroll
    for (int e = 0; e < 16; ++e) {
      int lin = tid + e * 256;
      int i = lin >> 7, c = lin & 127;
      tile[i][c] = x[(b * 512 + k0 + i) * 128 + c];
    }
    __syncthreads();
    #pragma unroll
    for (int e = 0; e < 16; ++e) {
      int lin = tid + e * 256;
      int c = lin >> 5, i = lin & 31;
      int f = c >> 1, ri = c & 1;
      A1[(b * 64 + f) * 1024 + ri * 512 + k0 + i] = f2bf(tile[i][c]);
    }
  }
}

// ---------------- shared GEMM pieces ----------------
#define GLOAD16(gsrc, ldst) \
  __builtin_amdgcn_global_load_lds( \
      (const __attribute__((address_space(1))) void*)(gsrc), \
      (__attribute__((address_space(3))) void*)(ldst), 16, 0, 0)

#define WAIT_VMCNT6()  __builtin_amdgcn_s_waitcnt(0xF76)  /* vmcnt(6) */
#define WAIT_VMCNT0()  __builtin_amdgcn_s_waitcnt(0xF70)  /* vmcnt(0) */

// wave-tile 32x64: acc[2][4]; arow base warp_m*32, brow base warp_n*64
static __device__ __forceinline__ void gemm_compute64(
    const ushort* as, const ushort* bs, int arow, int brow, int g, int rx,
    floatx4 (&acc)[2][4]) {
  #pragma unroll
  for (int ks = 0; ks < 2; ++ks) {
    short8 af[2], bfr[4];
    const int chunk = ((ks << 2) + g) ^ rx;
    #pragma unroll
    for (int fm = 0; fm < 2; ++fm)
      af[fm] = *(const short8*)(as + (arow + fm * 16) * 64 + chunk * 8);
    #pragma unroll
    for (int fn = 0; fn < 4; ++fn)
      bfr[fn] = *(const short8*)(bs + (brow + fn * 16) * 64 + chunk * 8);
    #pragma unroll
    for (int fm = 0; fm < 2; ++fm)
      #pragma unroll
      for (int fn = 0; fn < 4; ++fn)
        acc[fm][fn] = __builtin_amdgcn_mfma_f32_16x16x32_bf16(
            af[fm], bfr[fn], acc[fm][fn], 0, 0, 0);
  }
}

// ---------------- GEMM1: C[4096,1024] = A1 * BT1^T, BM=64 BN=128, dbuf -----
__global__ __launch_bounds__(256, 2) void gemm1(
    const ushort* __restrict__ A, const ushort* __restrict__ Bt,
    float* __restrict__ C) {
  __shared__ __align__(16) ushort As[2][64 * 64];
  __shared__ __align__(16) ushort Bs[2][128 * 64];
  const int tid = threadIdx.x;
  const int wid = tid >> 6, lane = tid & 63;
  const int m0 = blockIdx.y * 64, n0 = blockIdx.x * 128;
  const int warp_m = wid >> 1, warp_n = wid & 1;

  floatx4 acc[2][4];
  #pragma unroll
  for (int i = 0; i < 2; ++i)
    #pragma unroll
    for (int j = 0; j < 4; ++j) acc[i][j] = (floatx4){0.f, 0.f, 0.f, 0.f};

  const int lr = lane >> 3, lc = lane & 7;
  const int swz = lc ^ lr;
  const ushort* aBase = A  + (size_t)(m0 + wid * 8 + lr) * GK + swz * 8;
  const ushort* bBase = Bt + (size_t)(n0 + wid * 8 + lr) * GK + swz * 8;

  const int lane15 = lane & 15;
  const int g = lane >> 4;
  const int rx = lane & 7;
  const int arow = warp_m * 32 + lane15;
  const int brow = warp_n * 64 + lane15;

#define STAGE_G1(buf, kk0) do { \
    _Pragma("unroll") \
    for (int p = 0; p < 2; ++p) \
      GLOAD16(aBase + (size_t)(p * 32) * GK + (kk0), &As[buf][(p * 32 + wid * 8) * 64]); \
    _Pragma("unroll") \
    for (int p = 0; p < 4; ++p) \
      GLOAD16(bBase + (size_t)(p * 32) * GK + (kk0), &Bs[buf][(p * 32 + wid * 8) * 64]); \
    } while (0)

  STAGE_G1(0, 0);
  for (int t = 0; t < 15; ++t) {
    STAGE_G1((t + 1) & 1, (t + 1) * 64);
    WAIT_VMCNT6();
    __builtin_amdgcn_s_barrier();
    __builtin_amdgcn_sched_barrier(0);
    gemm_compute64(&As[t & 1][0], &Bs[t & 1][0], arow, brow, g, rx, acc);
    __builtin_amdgcn_sched_barrier(0);
    __builtin_amdgcn_s_barrier();
  }
  WAIT_VMCNT0();
  __builtin_amdgcn_s_barrier();
  gemm_compute64(&As[1][0], &Bs[1][0], arow, brow, g, rx, acc);

  #pragma unroll
  for (int fm = 0; fm < 2; ++fm)
    #pragma unroll
    for (int fn = 0; fn < 4; ++fn)
      #pragma unroll
      for (int i = 0; i < 4; ++i) {
        int gm = m0 + warp_m * 32 + fm * 16 + g * 4 + i;
        int gn = n0 + warp_n * 64 + fn * 16 + lane15;
        C[(size_t)gm * 1024 + gn] = acc[fm][fn][i];
      }
#undef STAGE_G1
}

// ---- GEMM2: out = gather(Ftb) * BT2^T, BM=64 (one b per block), BN=128 ----
// n-slot s in [0,128): kk = bx*64 + (s&63) + (s>>6)*512  (ri = s>>6)
__global__ __launch_bounds__(256, 2) void gemm2(
    const ushort* __restrict__ Ftb, const ushort* __restrict__ Bt,
    float* __restrict__ out) {
  __shared__ __align__(16) ushort smem[2 * 64 * 64 + 2 * 128 * 64];
  ushort (*As)[64 * 64] = (ushort(*)[64 * 64])smem;
  ushort (*Bs)[128 * 64] = (ushort(*)[128 * 64])(smem + 2 * 64 * 64);
  float* CT = (float*)smem;                     // [128][65] after compute
  const int tid = threadIdx.x;
  const int wid = tid >> 6, lane = tid & 63;
  const int by = blockIdx.y, bx = blockIdx.x;   // by = batch b
  const int warp_m = wid >> 1, warp_n = wid & 1;

  floatx4 acc[2][4];
  #pragma unroll
  for (int i = 0; i < 2; ++i)
    #pragma unroll
    for (int j = 0; j < 4; ++j) acc[i][j] = (floatx4){0.f, 0.f, 0.f, 0.f};

  const int lr = lane >> 3, lc = lane & 7;
  const int swz = lc ^ lr;

  // A: frame rows f = p*32 + wid*8 + lr of batch by: Ftb[by*TLEN + f*256 + k]
  const ushort* aBase = Ftb + (size_t)by * TLEN + (wid * 8 + lr) * 256 + swz * 8;
  // B: permuted rows (both ri halves)
  const ushort* bB0 = Bt + (size_t)(bx * 64 + wid * 8 + lr) * GK + swz * 8;

  const int lane15 = lane & 15;
  const int g = lane >> 4;
  const int rx = lane & 7;
  const int arow = warp_m * 32 + lane15;
  const int brow = warp_n * 64 + lane15;

#define STAGE_G2(buf, kk0) do { \
    _Pragma("unroll") \
    for (int p = 0; p < 2; ++p) \
      GLOAD16(aBase + (size_t)(p * 32) * 256 + (kk0), &As[buf][(p * 32 + wid * 8) * 64]); \
    _Pragma("unroll") \
    for (int p = 0; p < 4; ++p) { \
      size_t boff = (size_t)((p & 1) * 32 + (p >> 1) * 512) * GK; \
      GLOAD16(bB0 + boff + (kk0), &Bs[buf][(((p >> 1) * 64 + (p & 1) * 32) + wid * 8) * 64]); \
    } } while (0)

  STAGE_G2(0, 0);
  for (int t = 0; t < 15; ++t) {
    STAGE_G2((t + 1) & 1, (t + 1) * 64);
    WAIT_VMCNT6();
    __builtin_amdgcn_s_barrier();
    __builtin_amdgcn_sched_barrier(0);
    gemm_compute64(&As[t & 1][0], &Bs[t & 1][0], arow, brow, g, rx, acc);
    __builtin_amdgcn_sched_barrier(0);
    __builtin_amdgcn_s_barrier();
  }
  WAIT_VMCNT0();
  __builtin_amdgcn_s_barrier();
  gemm_compute64(&As[1][0], &Bs[1][0], arow, brow, g, rx, acc);

  // epilogue: acc -> CT[s][f] (padded 65), then coalesced 512B row writes
  __syncthreads();
  #pragma unroll
  for (int fm = 0; fm < 2; ++fm)
    #pragma unroll
    for (int fn = 0; fn < 4; ++fn)
      #pragma unroll
      for (int i = 0; i < 4; ++i) {
        int s    = warp_n * 64 + fn * 16 + lane15;
        int fcol = warp_m * 32 + fm * 16 + g * 4 + i;
        CT[s * 65 + fcol] = acc[fm][fn][i];
      }
  __syncthreads();
  // out[((by*512 + bx*64 + r))*128 + q*4 ...]: r k-local, q float4-quad
  #pragma unroll
  for (int e = 0; e < 8; ++e) {
    int it = tid + e * 256;
    int r = it >> 5, q = it & 31;
    float4 v;
    v.x = CT[r * 65 + 2 * q];             // f=2q,  ri=0
    v.y = CT[(64 + r) * 65 + 2 * q];      // f=2q,  ri=1
    v.z = CT[r * 65 + 2 * q + 1];         // f=2q+1,ri=0
    v.w = CT[(64 + r) * 65 + 2 * q + 1];  // f=2q+1,ri=1
    *(float4*)&out[((size_t)(by * 512 + bx * 64 + r)) * 128 + q * 4] = v;
  }
#undef STAGE_G2
}

// ---------------- fused overlap-add + filtfilt -> bf16 signal ----------------
#define SWZ(r) ((r) ^ (((r) >> 6) & 31))

static __device__ __forceinline__ float oa_sample(const float* __restrict__ frb,
                                                  int tau) {
  int fhi = tau >> 8;
  int flo = fhi - 3; if (flo < 0) flo = 0;
  if (fhi > 63) fhi = 63;
  float sum = 0.f;
  for (int f = flo; f <= fhi; ++f) {
    int off = tau - (f << 8);
    if (off < NW) sum += frb[(size_t)f * 1024 + off];
  }
  return sum;
}

#define IIR_STEP(x, y)                                   \
  float y = fmaf(cf.b0, (x), z0);                        \
  z0 = fmaf(-cf.a1, y, fmaf(cf.b1, (x), z1));            \
  z1 = fmaf(-cf.a2, y, fmaf(cf.b2, (x), z2));            \
  z2 = fmaf(-cf.a3, y, fmaf(cf.b3, (x), z3));            \
  z3 = fmaf(-cf.a4, y, fmaf(cf.b4, (x), z4));            \
  z4 = fmaf(-cf.a5, y, cf.b5 * (x));

__global__ __launch_bounds__(256) void oa_iir(const float* __restrict__ Fr,
                                              ushort* __restrict__ Ftb,
                                              IirCoef cf) {
  __shared__ float bufX[SPAN];   // xe, later y2
  __shared__ float bufY[SPAN];   // y1
  const int blk = blockIdx.x;
  const int b = blk >> 2, sp = blk & 3;
  const int lo = sp * BS;
  const int hi = (lo + BS < TLEN) ? lo + BS : TLEN;     // filt range [lo,hi)
  const int F0 = (sp == 0) ? 0 : lo + PADL;             // fwd output xe-range
  int F1 = hi + PADL + 128; if (F1 > LXLEN) F1 = LXLEN;
  const int XB = (sp == 0) ? 0 : F0 - 64;               // xe LDS base
  const int xspan = F1 - XB;                            // <= SPAN
  const float* frb = Fr + (size_t)b * 64 * 1024;

  // phase 1: xe -> bufX (reflect-pad over overlap-add, computed on the fly)
  for (int rel = threadIdx.x; rel < xspan; rel += 256) {
    int p = XB + rel;
    float v;
    if (p < PADL)                 v = 2.f * oa_sample(frb, 0) - oa_sample(frb, PADL - p);
    else if (p < PADL + TLEN)     v = oa_sample(frb, p - PADL);
    else { int j = p - (PADL + TLEN);
           v = 2.f * oa_sample(frb, TLEN - 1) - oa_sample(frb, TLEN - 2 - j); }
    bufX[SWZ(rel)] = v;
  }
  __syncthreads();

  // phase 2: forward IIR chunks (64 warm + 64 live), bufX -> bufY
  {
    int nch = (F1 - F0 + 63) >> 6;
    int c = threadIdx.x;
    if (c < nch) {
      int os = F0 + (c << 6);
      int oe = os + 64; if (oe > F1) oe = F1;
      float z0, z1, z2, z3, z4;
      int i;
      if (sp == 0 && c == 0) {
        float x0 = bufX[SWZ(0)];
        z0 = cf.zi0 * x0; z1 = cf.zi1 * x0; z2 = cf.zi2 * x0;
        z3 = cf.zi3 * x0; z4 = cf.zi4 * x0;
        i = 0;
      } else {
        z0 = z1 = z2 = z3 = z4 = 0.f;
        i = os - 64;
        #pragma unroll 4
        for (; i < os; ++i) { float x = bufX[SWZ(i - XB)]; IIR_STEP(x, y); (void)y; }
      }
      #pragma unroll 4
      for (; i < oe; ++i) {
        float x = bufX[SWZ(i - XB)];
        IIR_STEP(x, y);
        bufY[SWZ(i - XB)] = y;
      }
    }
  }
  __syncthreads();

  // phase 3: backward IIR chunks (absolute 64-aligned reversed grid), bufY -> bufX
  {
    const int R0 = TLEN + PADL - hi;          // owned reversed range [R0, R1)
    const int R1 = LXLEN - lo - PADL;
    int k_lo = R0 >> 6, k_hi = (R1 - 1) >> 6;
    int k = k_lo + threadIdx.x;
    if (k <= k_hi) {
      int rs = k << 6;
      int re = rs + 64; if (re > R1) re = R1;
      float z0, z1, z2, z3, z4;
      int i;
      if (k == 0) {
        float x0 = bufY[SWZ(LXLEN - 1 - XB)];
        z0 = cf.zi0 * x0; z1 = cf.zi1 * x0; z2 = cf.zi2 * x0;
        z3 = cf.zi3 * x0; z4 = cf.zi4 * x0;
        i = 0;
      } else {
        z0 = z1 = z2 = z3 = z4 = 0.f;
        i = rs - 64;
        #pragma unroll 4
        for (; i < rs; ++i) { float x = bufY[SWZ(LXLEN - 1 - i - XB)]; IIR_STEP(x, y); (void)y; }
      }
      #pragma unroll 4
      for (; i < re; ++i) {
        float x = bufY[SWZ(LXLEN - 1 - i - XB)];
        IIR_STEP(x, y);
        if (i >= R0) bufX[SWZ(LXLEN - 1 - i - XB)] = y;
      }
    }
  }
  __syncthreads();

  // phase 4: coalesced bf16 write of owned filt range
  for (int t = lo + threadIdx.x; t < hi; t += 256)
    Ftb[(size_t)b * TLEN + t] = f2bf(bufX[SWZ(t + PADL - XB)]);
  // zero-pad tail so gemm2's K-padding reads stay finite
  if (b == NB - 1 && sp == 3)
    for (int t = threadIdx.x; t < 1024; t += 256)
      Ftb[(size_t)NB * TLEN + t] = 0;
}

// ---------------- host: butter(5,0.5) + lfilter_zi ----------------
static void solve5(double M[5][5], double v[5], double outv[5]) {
  for (int col = 0; col < 5; ++col) {
    int piv = col;
    for (int r = col + 1; r < 5; ++r)
      if (std::fabs(M[r][col]) > std::fabs(M[piv][col])) piv = r;
    if (piv != col) {
      for (int c = 0; c < 5; ++c) std::swap(M[col][c], M[piv][c]);
      std::swap(v[col], v[piv]);
    }
    double d = M[col][col];
    for (int r = col + 1; r < 5; ++r) {
      double f = M[r][col] / d;
      for (int c = col; c < 5; ++c) M[r][c] -= f * M[col][c];
      v[r] -= f * v[col];
    }
  }
  for (int r = 4; r >= 0; --r) {
    double s = v[r];
    for (int c = r + 1; c < 5; ++c) s -= M[r][c] * outv[c];
    outv[r] = s / M[r][r];
  }
}

static IirCoef make_coef() {
  const double PI = 3.14159265358979323846;
  std::complex<double> p[5];
  for (int i = 0; i < 5; ++i) {
    double m = -4.0 + 2.0 * i;
    p[i] = -std::exp(std::complex<double>(0.0, PI * m / 10.0));
  }
  double fs = 2.0;
  double warped = 2.0 * fs * std::tan(PI * 0.5 / fs);
  for (int i = 0; i < 5; ++i) p[i] *= warped;
  double kgain = std::pow(warped, 5.0);
  double fs2 = 2.0 * fs;
  std::complex<double> pd[5], prod(1.0, 0.0);
  for (int i = 0; i < 5; ++i) {
    pd[i] = (fs2 + p[i]) / (fs2 - p[i]);
    prod *= (fs2 - p[i]);
  }
  double kd = kgain * std::real(1.0 / prod);
  double b[6] = {kd, 5 * kd, 10 * kd, 10 * kd, 5 * kd, kd};
  std::complex<double> c[6] = {{1,0},{0,0},{0,0},{0,0},{0,0},{0,0}};
  for (int i = 0; i < 5; ++i)
    for (int j = i + 1; j >= 1; --j)
      c[j] -= pd[i] * c[j - 1];
  double a[6]; for (int i = 0; i < 6; ++i) a[i] = c[i].real();
  double M[5][5], v[5];
  for (int r = 0; r < 5; ++r)
    for (int cc = 0; cc < 5; ++cc) {
      double Af = 0.0;
      if (cc == 0) Af = -a[r + 1];
      if (cc == r + 1) Af = 1.0;
      M[r][cc] = (r == cc ? 1.0 : 0.0) - Af;
    }
  for (int r = 0; r < 5; ++r) v[r] = b[r + 1] - a[r + 1] * b[0];
  double zi[5];
  solve5(M, v, zi);
  IirCoef cf;
  cf.b0 = (float)b[0]; cf.b1 = (float)b[1]; cf.b2 = (float)b[2];
  cf.b3 = (float)b[3]; cf.b4 = (float)b[4]; cf.b5 = (float)b[5];
  cf.a1 = (float)a[1]; cf.a2 = (float)a[2]; cf.a3 = (float)a[3];
  cf.a4 = (float)a[4]; cf.a5 = (float)a[5];
  cf.zi0 = (float)zi[0]; cf.zi1 = (float)zi[1]; cf.zi2 = (float)zi[2];
  cf.zi3 = (float)zi[3]; cf.zi4 = (float)zi[4];
  return cf;
}

extern "C" void kernel_launch(void* const* d_in, const int* in_sizes, int n_in,
                              void* d_out, int out_size, void* d_ws, size_t ws_size,
                              hipStream_t stream) {
  const float* x = (const float*)d_in[0];
  float* out = (float*)d_out;

  // workspace layout
  ushort* BT1 = (ushort*)d_ws;                   // 1024*1024 bf16
  ushort* BT2 = BT1 + 1024 * 1024;               // 1024*1024 bf16
  ushort* A1  = BT2 + 1024 * 1024;               // 4096*1024 bf16
  ushort* Ftb = A1 + (size_t)NFRAMES * 1024;     // NB*TLEN + 1024 bf16
  float*  Fr  = (float*)(Ftb + (size_t)NB * TLEN + 1024);  // 4096*1024 f32
  size_t need = (size_t)((char*)(Fr + (size_t)NFRAMES * 1024) - (char*)d_ws);
  if (ws_size < need) return;

  IirCoef cf = make_coef();

  prep<<<9216, 256, 0, stream>>>(x, BT1, BT2, A1);
  gemm1<<<dim3(8, 64), 256, 0, stream>>>(A1, BT1, Fr);
  oa_iir<<<NB * 4, 256, 0, stream>>>(Fr, Ftb, cf);
  gemm2<<<dim3(8, 64), 256, 0, stream>>>(Ftb, BT2, out);
}

// Round 6
// 80.975 us; speedup vs baseline: 8.7969x; 1.0234x over previous
//
#include <hip/hip_runtime.h>
#include <cmath>
#include <complex>
#include <algorithm>

#define NW      1022
#define NB      64
#define TLEN    17150   /* HOP*(F-1)+W */
#define PADL    18
#define LXLEN   17186   /* TLEN + 2*PADL */
#define NFRAMES 4096    /* NB*64 */
#define BS      4288    /* samples per oa_iir split (4 splits/row) */
#define SPAN    4480    /* LDS floats per buffer in oa_iir */

typedef __attribute__((ext_vector_type(8))) short short8;
typedef __attribute__((ext_vector_type(4))) float floatx4;

struct IirCoef {
  float b0,b1,b2,b3,b4,b5;
  float a1,a2,a3,a4,a5;
  float zi0,zi1,zi2,zi3,zi4;
};

static __device__ __forceinline__ ushort f2bf(float f) {
  uint32_t u = __builtin_bit_cast(uint32_t, f);
  uint32_t r = (u + 0x7FFFu + ((u >> 16) & 1u)) >> 16;   // RNE
  return (ushort)r;
}
static __device__ __forceinline__ float bf2f(ushort u) {
  return __builtin_bit_cast(float, (uint32_t)u << 16);
}

// fp32-exact (k*t) mod 1022 (k,t <= 511 so k*t < 2^18), then radians
static __device__ __forceinline__ float phase_mod(int k, int t) {
  const float TPN = 6.2831853071795864769f / 1022.f;
  float kt = (float)(k * t);
  float q = floorf(kt * (1.0f / 1022.0f));
  float r = kt - q * 1022.0f;
  if (r < 0.f) r += 1022.f;
  if (r >= 1022.f) r -= 1022.f;
  return r * TPN;
}

// ---------------- fused prep ----------------
// blocks [0,1024): cb1/sb1 [t][k]   (irfft half-bases, no syn)
// blocks [1024,2048): cb2/sb2 [k][t] (rfft half-bases, fw folded in)
// block 2048: syn table (f32[1022])
// blocks [2049,3073): A1 transpose tiles
__global__ __launch_bounds__(256) void prep(const float* __restrict__ x,
                                            ushort* __restrict__ cb1,
                                            ushort* __restrict__ sb1,
                                            ushort* __restrict__ cb2,
                                            ushort* __restrict__ sb2,
                                            float* __restrict__ synT,
                                            ushort* __restrict__ A1) {
  __shared__ float tile[32][129];
  const float TPN = 6.2831853071795864769f / 1022.f;
  int bid = blockIdx.x;
  if (bid < 1024) {
    int idx = bid * 256 + threadIdx.x;     // t*512 + k
    int t = idx >> 9, k = idx & 511;
    float arg = phase_mod(k, t);
    float s = ((k == 0 || k == 511) ? 1.f : 2.f) * (1.f / 1022.f);
    cb1[idx] = f2bf(__cosf(arg) * s);
    sb1[idx] = f2bf(-__sinf(arg) * s);
  } else if (bid < 2048) {
    int idx = (bid - 1024) * 256 + threadIdx.x;  // k*512 + t
    int k = idx >> 9, t = idx & 511;
    float fw = 0.5f - 0.5f * __cosf((float)t * TPN);
    float arg = phase_mod(k, t);
    cb2[idx] = f2bf(fw * __cosf(arg));
    sb2[idx] = f2bf(-fw * __sinf(arg));
  } else if (bid == 2048) {
    for (int t = threadIdx.x; t < NW; t += 256) {
      float fw = 0.5f - 0.5f * __cosf((float)t * TPN);
      float den = 0.f;
      int tm = t & 255;
      #pragma unroll
      for (int j = 0; j < 4; ++j) {
        int u = tm + (j << 8);
        if (u < NW) { float w = 0.5f - 0.5f * __cosf((float)u * TPN); den += w * w; }
      }
      synT[t] = fw / den;
    }
  } else {
    int tb = bid - 2049;
    int b  = tb >> 4;
    int k0 = (tb & 15) << 5;
    int tid = threadIdx.x;
    #pragma unroll
    for (int e = 0; e < 16; ++e) {
      int lin = tid + e * 256;
      int i = lin >> 7, c = lin & 127;
      tile[i][c] = x[(b * 512 + k0 + i) * 128 + c];
    }
    __syncthreads();
    #pragma unroll
    for (int e = 0; e < 16; ++e) {
      int lin = tid + e * 256;
      int c = lin >> 5, i = lin & 31;
      int f = c >> 1, ri = c & 1;
      A1[(b * 64 + f) * 1024 + ri * 512 + k0 + i] = f2bf(tile[i][c]);
    }
  }
}

// ---------------- shared GEMM pieces ----------------
#define GLOAD16(gsrc, ldst) \
  __builtin_amdgcn_global_load_lds( \
      (const __attribute__((address_space(1))) void*)(gsrc), \
      (__attribute__((address_space(3))) void*)(ldst), 16, 0, 0)

#define WAIT_VMCNT8()  __builtin_amdgcn_s_waitcnt(0xF78)  /* vmcnt(8) */
#define WAIT_VMCNT6()  __builtin_amdgcn_s_waitcnt(0xF76)  /* vmcnt(6) */
#define WAIT_VMCNT0()  __builtin_amdgcn_s_waitcnt(0xF70)  /* vmcnt(0) */

// wave-tile 32xN: acc[2][4]; reads rows (arow+fm*16), (brow+fn*16) of chunked tiles
static __device__ __forceinline__ void gemm_compute64(
    const ushort* as, const ushort* bs, int arow, int brow, int g, int rx,
    floatx4 (&acc)[2][4]) {
  #pragma unroll
  for (int ks = 0; ks < 2; ++ks) {
    short8 af[2], bfr[4];
    const int chunk = ((ks << 2) + g) ^ rx;
    #pragma unroll
    for (int fm = 0; fm < 2; ++fm)
      af[fm] = *(const short8*)(as + (arow + fm * 16) * 64 + chunk * 8);
    #pragma unroll
    for (int fn = 0; fn < 4; ++fn)
      bfr[fn] = *(const short8*)(bs + (brow + fn * 16) * 64 + chunk * 8);
    #pragma unroll
    for (int fm = 0; fm < 2; ++fm)
      #pragma unroll
      for (int fn = 0; fn < 4; ++fn)
        acc[fm][fn] = __builtin_amdgcn_mfma_f32_16x16x32_bf16(
            af[fm], bfr[fn], acc[fm][fn], 0, 0, 0);
  }
}

// ---- GEMM1: U = A1Re*cb1^T, V = A1Im*sb1^T; [4096x512]x[512x512] each ----
// grid x: uv*4 + nb (BN=128 over t), y: 64 M-blocks
__global__ __launch_bounds__(256, 2) void gemm1(
    const ushort* __restrict__ A1, const ushort* __restrict__ cb1,
    const ushort* __restrict__ sb1, float* __restrict__ U,
    float* __restrict__ V) {
  __shared__ __align__(16) ushort As[2][64 * 64];
  __shared__ __align__(16) ushort Bs[2][128 * 64];
  const int tid = threadIdx.x;
  const int wid = tid >> 6, lane = tid & 63;
  const int uv = blockIdx.x >> 2, nb = blockIdx.x & 3;
  const int m0 = blockIdx.y * 64, n0 = nb * 128;
  const int warp_m = wid >> 1, warp_n = wid & 1;
  const ushort* Bt = uv ? sb1 : cb1;
  float* C = uv ? V : U;

  floatx4 acc[2][4];
  #pragma unroll
  for (int i = 0; i < 2; ++i)
    #pragma unroll
    for (int j = 0; j < 4; ++j) acc[i][j] = (floatx4){0.f, 0.f, 0.f, 0.f};

  const int lr = lane >> 3, lc = lane & 7;
  const int swz = lc ^ lr;
  const ushort* aBase = A1 + (size_t)(m0 + wid * 8 + lr) * 1024 + uv * 512 + swz * 8;
  const ushort* bBase = Bt + (size_t)(n0 + wid * 8 + lr) * 512 + swz * 8;

  const int lane15 = lane & 15;
  const int g = lane >> 4;
  const int rx = lane & 7;
  const int arow = warp_m * 32 + lane15;
  const int brow = warp_n * 64 + lane15;

#define STAGE_G1(buf, kk0) do { \
    _Pragma("unroll") \
    for (int p = 0; p < 2; ++p) \
      GLOAD16(aBase + (size_t)(p * 32) * 1024 + (kk0), &As[buf][(p * 32 + wid * 8) * 64]); \
    _Pragma("unroll") \
    for (int p = 0; p < 4; ++p) \
      GLOAD16(bBase + (size_t)(p * 32) * 512 + (kk0), &Bs[buf][(p * 32 + wid * 8) * 64]); \
    } while (0)

  STAGE_G1(0, 0);
  for (int t = 0; t < 7; ++t) {
    STAGE_G1((t + 1) & 1, (t + 1) * 64);
    WAIT_VMCNT6();
    __builtin_amdgcn_s_barrier();
    __builtin_amdgcn_sched_barrier(0);
    gemm_compute64(&As[t & 1][0], &Bs[t & 1][0], arow, brow, g, rx, acc);
    __builtin_amdgcn_sched_barrier(0);
    __builtin_amdgcn_s_barrier();
  }
  WAIT_VMCNT0();
  __builtin_amdgcn_s_barrier();
  gemm_compute64(&As[1][0], &Bs[1][0], arow, brow, g, rx, acc);

  #pragma unroll
  for (int fm = 0; fm < 2; ++fm)
    #pragma unroll
    for (int fn = 0; fn < 4; ++fn)
      #pragma unroll
      for (int i = 0; i < 4; ++i) {
        int gm = m0 + warp_m * 32 + fm * 16 + g * 4 + i;
        int gn = n0 + warp_n * 64 + fn * 16 + lane15;
        C[(size_t)gm * 512 + gn] = acc[fm][fn][i];
      }
#undef STAGE_G1
}

// ---- GEMM2: Re = Ae*cb2^T, Im = Ao*sb2^T, fused + transpose epilogue -----
// grid x: kx (8 x BN=64 k-cols), y: by (batch). Waves: (warp_m, half=Re/Im).
__global__ __launch_bounds__(256, 2) void gemm2(
    const ushort* __restrict__ Ae, const ushort* __restrict__ Ao,
    const ushort* __restrict__ cb2, const ushort* __restrict__ sb2,
    float* __restrict__ out) {
  __shared__ __align__(16) ushort smem[32768];   // sA: [buf][eo] 4x4096, sB: +16384
  const int tid = threadIdx.x;
  const int wid = tid >> 6, lane = tid & 63;
  const int kx = blockIdx.x, by = blockIdx.y;
  const int warp_m = wid >> 1, half = wid & 1;

  floatx4 acc[2][4];
  #pragma unroll
  for (int i = 0; i < 2; ++i)
    #pragma unroll
    for (int j = 0; j < 4; ++j) acc[i][j] = (floatx4){0.f, 0.f, 0.f, 0.f};

  const int lr = lane >> 3, lc = lane & 7;
  const int swz = lc ^ lr;
  const size_t arow_g = (size_t)(by * 64 + wid * 8 + lr) * 512 + swz * 8;
  const size_t brow_g = (size_t)(kx * 64 + wid * 8 + lr) * 512 + swz * 8;
  const ushort* aeB = Ae + arow_g;
  const ushort* aoB = Ao + arow_g;
  const ushort* cbB = cb2 + brow_g;
  const ushort* sbB = sb2 + brow_g;

  const int lane15 = lane & 15;
  const int g = lane >> 4;
  const int rx = lane & 7;
  const int arow = warp_m * 32 + lane15;

#define STAGE_G2(buf, kk0) do { \
    _Pragma("unroll") \
    for (int p = 0; p < 2; ++p) { \
      int ld = (p * 32 + wid * 8) * 64; \
      size_t go = (size_t)(p * 32) * 512 + (kk0); \
      GLOAD16(aeB + go, &smem[(buf) * 2 * 4096 + ld]); \
      GLOAD16(aoB + go, &smem[((buf) * 2 + 1) * 4096 + ld]); \
      GLOAD16(cbB + go, &smem[16384 + (buf) * 2 * 4096 + ld]); \
      GLOAD16(sbB + go, &smem[16384 + ((buf) * 2 + 1) * 4096 + ld]); \
    } } while (0)

  STAGE_G2(0, 0);
  for (int t = 0; t < 7; ++t) {
    STAGE_G2((t + 1) & 1, (t + 1) * 64);
    WAIT_VMCNT8();
    __builtin_amdgcn_s_barrier();
    __builtin_amdgcn_sched_barrier(0);
    gemm_compute64(&smem[((t & 1) * 2 + half) * 4096],
                   &smem[16384 + ((t & 1) * 2 + half) * 4096],
                   arow, lane15, g, rx, acc);
    __builtin_amdgcn_sched_barrier(0);
    __builtin_amdgcn_s_barrier();
  }
  WAIT_VMCNT0();
  __builtin_amdgcn_s_barrier();
  gemm_compute64(&smem[(2 + half) * 4096], &smem[16384 + (2 + half) * 4096],
                 arow, lane15, g, rx, acc);

  // epilogue: acc -> CT[k][f*2+half] (stride 132), then coalesced 512B rows
  __syncthreads();
  float* CT = (float*)smem;    // 64*132 floats = 33792B, safely inside 64KB
  #pragma unroll
  for (int fm = 0; fm < 2; ++fm)
    #pragma unroll
    for (int fn = 0; fn < 4; ++fn)
      #pragma unroll
      for (int i = 0; i < 4; ++i) {
        int f = warp_m * 32 + fm * 16 + g * 4 + i;
        int k = fn * 16 + lane15;
        CT[k * 132 + f * 2 + half] = acc[fm][fn][i];
      }
  __syncthreads();
  #pragma unroll
  for (int e = 0; e < 8; ++e) {
    int it = tid + e * 256;
    int r = it >> 5, q = it & 31;
    float4 v = *(float4*)&CT[r * 132 + q * 4];
    *(float4*)&out[((size_t)(by * 512 + kx * 64 + r)) * 128 + q * 4] = v;
  }
#undef STAGE_G2
}

// ---------------- fold: Ae/Ao from bf16 signal ----------------
__global__ __launch_bounds__(256) void fold(const ushort* __restrict__ Ftb,
                                            ushort* __restrict__ Ae,
                                            ushort* __restrict__ Ao) {
  int idx = blockIdx.x * 256 + threadIdx.x;   // 4096*512
  int fid = idx >> 9, t = idx & 511;
  int b = fid >> 6, f = fid & 63;
  const ushort* base = Ftb + (size_t)b * TLEN + (f << 8);
  float s1 = bf2f(base[t]);
  float s2 = (t == 511) ? 0.f : bf2f(base[1022 - t]);  // t=0 pair is dead (fw[0]=0)
  Ae[idx] = f2bf(s1 + s2);
  Ao[idx] = f2bf(s1 - s2);
}

// ---------------- fused overlap-add + filtfilt -> bf16 signal ----------------
#define SWZ(r) ((r) ^ (((r) >> 6) & 31))

static __device__ __forceinline__ float oa_sample(const float* __restrict__ ub,
                                                  const float* __restrict__ vb,
                                                  const float* __restrict__ synl,
                                                  int tau) {
  int fhi = tau >> 8;
  int flo = fhi - 3; if (flo < 0) flo = 0;
  if (fhi > 63) fhi = 63;
  float sum = 0.f;
  for (int f = flo; f <= fhi; ++f) {
    int off = tau - (f << 8);
    if (off < NW) {
      int o2 = (off < 512) ? off : 1022 - off;
      float u = ub[f * 512 + o2], v = vb[f * 512 + o2];
      float y = (off < 512) ? u + v : u - v;
      sum += synl[off] * y;
    }
  }
  return sum;
}

#define IIR_STEP(x, y)                                   \
  float y = fmaf(cf.b0, (x), z0);                        \
  z0 = fmaf(-cf.a1, y, fmaf(cf.b1, (x), z1));            \
  z1 = fmaf(-cf.a2, y, fmaf(cf.b2, (x), z2));            \
  z2 = fmaf(-cf.a3, y, fmaf(cf.b3, (x), z3));            \
  z3 = fmaf(-cf.a4, y, fmaf(cf.b4, (x), z4));            \
  z4 = fmaf(-cf.a5, y, cf.b5 * (x));

__global__ __launch_bounds__(256) void oa_iir(const float* __restrict__ U,
                                              const float* __restrict__ V,
                                              const float* __restrict__ synT,
                                              ushort* __restrict__ Ftb,
                                              IirCoef cf) {
  __shared__ float bufX[SPAN];   // xe, later y2
  __shared__ float bufY[SPAN];   // y1
  __shared__ float synl[NW];
  const int blk = blockIdx.x;
  const int b = blk >> 2, sp = blk & 3;
  const int lo = sp * BS;
  const int hi = (lo + BS < TLEN) ? lo + BS : TLEN;     // filt range [lo,hi)
  const int F0 = (sp == 0) ? 0 : lo + PADL;             // fwd output xe-range
  int F1 = hi + PADL + 128; if (F1 > LXLEN) F1 = LXLEN;
  const int XB = (sp == 0) ? 0 : F0 - 64;               // xe LDS base
  const int xspan = F1 - XB;                            // <= SPAN
  const float* ub = U + (size_t)(b * 64) * 512;
  const float* vb = V + (size_t)(b * 64) * 512;

  for (int i = threadIdx.x; i < NW; i += 256) synl[i] = synT[i];
  __syncthreads();

  // phase 1: xe -> bufX (reflect-pad over overlap-add, computed on the fly)
  for (int rel = threadIdx.x; rel < xspan; rel += 256) {
    int p = XB + rel;
    float v;
    if (p < PADL)
      v = 2.f * oa_sample(ub, vb, synl, 0) - oa_sample(ub, vb, synl, PADL - p);
    else if (p < PADL + TLEN)
      v = oa_sample(ub, vb, synl, p - PADL);
    else {
      int j = p - (PADL + TLEN);
      v = 2.f * oa_sample(ub, vb, synl, TLEN - 1) - oa_sample(ub, vb, synl, TLEN - 2 - j);
    }
    bufX[SWZ(rel)] = v;
  }
  __syncthreads();

  // phase 2: forward IIR chunks (64 warm + 64 live), bufX -> bufY
  {
    int nch = (F1 - F0 + 63) >> 6;
    int c = threadIdx.x;
    if (c < nch) {
      int os = F0 + (c << 6);
      int oe = os + 64; if (oe > F1) oe = F1;
      float z0, z1, z2, z3, z4;
      int i;
      if (sp == 0 && c == 0) {
        float x0 = bufX[SWZ(0)];
        z0 = cf.zi0 * x0; z1 = cf.zi1 * x0; z2 = cf.zi2 * x0;
        z3 = cf.zi3 * x0; z4 = cf.zi4 * x0;
        i = 0;
      } else {
        z0 = z1 = z2 = z3 = z4 = 0.f;
        i = os - 64;
        #pragma unroll 4
        for (; i < os; ++i) { float x = bufX[SWZ(i - XB)]; IIR_STEP(x, y); (void)y; }
      }
      #pragma unroll 4
      for (; i < oe; ++i) {
        float x = bufX[SWZ(i - XB)];
        IIR_STEP(x, y);
        bufY[SWZ(i - XB)] = y;
      }
    }
  }
  __syncthreads();

  // phase 3: backward IIR chunks (absolute 64-aligned reversed grid), bufY -> bufX
  {
    const int R0 = TLEN + PADL - hi;          // owned reversed range [R0, R1)
    const int R1 = LXLEN - lo - PADL;
    int k_lo = R0 >> 6, k_hi = (R1 - 1) >> 6;
    int k = k_lo + threadIdx.x;
    if (k <= k_hi) {
      int rs = k << 6;
      int re = rs + 64; if (re > R1) re = R1;
      float z0, z1, z2, z3, z4;
      int i;
      if (k == 0) {
        float x0 = bufY[SWZ(LXLEN - 1 - XB)];
        z0 = cf.zi0 * x0; z1 = cf.zi1 * x0; z2 = cf.zi2 * x0;
        z3 = cf.zi3 * x0; z4 = cf.zi4 * x0;
        i = 0;
      } else {
        z0 = z1 = z2 = z3 = z4 = 0.f;
        i = rs - 64;
        #pragma unroll 4
        for (; i < rs; ++i) { float x = bufY[SWZ(LXLEN - 1 - i - XB)]; IIR_STEP(x, y); (void)y; }
      }
      #pragma unroll 4
      for (; i < re; ++i) {
        float x = bufY[SWZ(LXLEN - 1 - i - XB)];
        IIR_STEP(x, y);
        if (i >= R0) bufX[SWZ(LXLEN - 1 - i - XB)] = y;
      }
    }
  }
  __syncthreads();

  // phase 4: coalesced bf16 write of owned filt range
  for (int t = lo + threadIdx.x; t < hi; t += 256)
    Ftb[(size_t)b * TLEN + t] = f2bf(bufX[SWZ(t + PADL - XB)]);
  // zero-pad tail so fold's t=0 pair reads stay finite for b=63
  if (b == NB - 1 && sp == 3)
    for (int t = threadIdx.x; t < 1024; t += 256)
      Ftb[(size_t)NB * TLEN + t] = 0;
}

// ---------------- host: butter(5,0.5) + lfilter_zi ----------------
static void solve5(double M[5][5], double v[5], double outv[5]) {
  for (int col = 0; col < 5; ++col) {
    int piv = col;
    for (int r = col + 1; r < 5; ++r)
      if (std::fabs(M[r][col]) > std::fabs(M[piv][col])) piv = r;
    if (piv != col) {
      for (int c = 0; c < 5; ++c) std::swap(M[col][c], M[piv][c]);
      std::swap(v[col], v[piv]);
    }
    double d = M[col][col];
    for (int r = col + 1; r < 5; ++r) {
      double f = M[r][col] / d;
      for (int c = col; c < 5; ++c) M[r][c] -= f * M[col][c];
      v[r] -= f * v[col];
    }
  }
  for (int r = 4; r >= 0; --r) {
    double s = v[r];
    for (int c = r + 1; c < 5; ++c) s -= M[r][c] * outv[c];
    outv[r] = s / M[r][r];
  }
}

static IirCoef make_coef() {
  const double PI = 3.14159265358979323846;
  std::complex<double> p[5];
  for (int i = 0; i < 5; ++i) {
    double m = -4.0 + 2.0 * i;
    p[i] = -std::exp(std::complex<double>(0.0, PI * m / 10.0));
  }
  double fs = 2.0;
  double warped = 2.0 * fs * std::tan(PI * 0.5 / fs);
  for (int i = 0; i < 5; ++i) p[i] *= warped;
  double kgain = std::pow(warped, 5.0);
  double fs2 = 2.0 * fs;
  std::complex<double> pd[5], prod(1.0, 0.0);
  for (int i = 0; i < 5; ++i) {
    pd[i] = (fs2 + p[i]) / (fs2 - p[i]);
    prod *= (fs2 - p[i]);
  }
  double kd = kgain * std::real(1.0 / prod);
  double b[6] = {kd, 5 * kd, 10 * kd, 10 * kd, 5 * kd, kd};
  std::complex<double> c[6] = {{1,0},{0,0},{0,0},{0,0},{0,0},{0,0}};
  for (int i = 0; i < 5; ++i)
    for (int j = i + 1; j >= 1; --j)
      c[j] -= pd[i] * c[j - 1];
  double a[6]; for (int i = 0; i < 6; ++i) a[i] = c[i].real();
  double M[5][5], v[5];
  for (int r = 0; r < 5; ++r)
    for (int cc = 0; cc < 5; ++cc) {
      double Af = 0.0;
      if (cc == 0) Af = -a[r + 1];
      if (cc == r + 1) Af = 1.0;
      M[r][cc] = (r == cc ? 1.0 : 0.0) - Af;
    }
  for (int r = 0; r < 5; ++r) v[r] = b[r + 1] - a[r + 1] * b[0];
  double zi[5];
  solve5(M, v, zi);
  IirCoef cf;
  cf.b0 = (float)b[0]; cf.b1 = (float)b[1]; cf.b2 = (float)b[2];
  cf.b3 = (float)b[3]; cf.b4 = (float)b[4]; cf.b5 = (float)b[5];
  cf.a1 = (float)a[1]; cf.a2 = (float)a[2]; cf.a3 = (float)a[3];
  cf.a4 = (float)a[4]; cf.a5 = (float)a[5];
  cf.zi0 = (float)zi[0]; cf.zi1 = (float)zi[1]; cf.zi2 = (float)zi[2];
  cf.zi3 = (float)zi[3]; cf.zi4 = (float)zi[4];
  return cf;
}

extern "C" void kernel_launch(void* const* d_in, const int* in_sizes, int n_in,
                              void* d_out, int out_size, void* d_ws, size_t ws_size,
                              hipStream_t stream) {
  const float* x = (const float*)d_in[0];
  float* out = (float*)d_out;

  // workspace layout (all chunks multiples of 16B)
  ushort* cb1 = (ushort*)d_ws;                   // 512*512
  ushort* sb1 = cb1 + 262144;
  ushort* cb2 = sb1 + 262144;
  ushort* sb2 = cb2 + 262144;
  float*  synT = (float*)(sb2 + 262144);         // 1024 f32
  ushort* A1  = (ushort*)(synT + 1024);          // 4096*1024
  ushort* Ftb = A1 + (size_t)NFRAMES * 1024;     // NB*TLEN + 1024
  ushort* Ae  = Ftb + (size_t)NB * TLEN + 1024;  // 4096*512
  ushort* Ao  = Ae + (size_t)NFRAMES * 512;
  float*  U   = (float*)(Ao + (size_t)NFRAMES * 512);  // 4096*512
  float*  V   = U + (size_t)NFRAMES * 512;
  size_t need = (size_t)((char*)(V + (size_t)NFRAMES * 512) - (char*)d_ws);
  if (ws_size < need) return;

  IirCoef cf = make_coef();

  prep<<<3073, 256, 0, stream>>>(x, cb1, sb1, cb2, sb2, synT, A1);
  gemm1<<<dim3(8, 64), 256, 0, stream>>>(A1, cb1, sb1, U, V);
  oa_iir<<<NB * 4, 256, 0, stream>>>(U, V, synT, Ftb, cf);
  fold<<<8192, 256, 0, stream>>>(Ftb, Ae, Ao);
  gemm2<<<dim3(8, 64), 256, 0, stream>>>(Ae, Ao, cb2, sb2, out);
}